// Round 3
// baseline (588.627 us; speedup 1.0000x reference)
//
#include <hip/hip_runtime.h>
#include <hip/hip_bf16.h>

#define BB 4
#define CC 256
#define HW 4096
#define DD 128

typedef __attribute__((ext_vector_type(8))) short bf16x8;
typedef __attribute__((ext_vector_type(4))) short bf16x4;
typedef __attribute__((ext_vector_type(4))) float f32x4;

static __device__ __forceinline__ void ld4(float* dst, const float* src) {
  float4 t = *(const float4*)src;
  dst[0] = t.x; dst[1] = t.y; dst[2] = t.z; dst[3] = t.w;
}

// float -> bf16 (RNE) raw bits
static __device__ __forceinline__ short f2b(float f) {
  unsigned u = __float_as_uint(f);
  u += 0x7fffu + ((u >> 16) & 1u);
  return (short)(u >> 16);
}
static __device__ __forceinline__ unsigned pk2(float lo, float hi) {
  return (unsigned)(unsigned short)f2b(lo) | ((unsigned)(unsigned short)f2b(hi) << 16);
}

// ---------------- K1: q/k/v 1x1 conv as LDS-staged bf16 MFMA.
// Per (pxtile, which, b): GEMM W(128x256) @ X(256x64px).
// Outputs: q,k -> (B,HW,128) bf16 (pre-transposed for attention);
//          v   -> (B,128,HW) bf16.
__global__ __launch_bounds__(256) void k_qkv_mfma(
    const float* __restrict__ src, const float* __restrict__ tgt,
    const float* __restrict__ Wq, const float* __restrict__ bq,
    const float* __restrict__ Wk, const float* __restrict__ bk,
    const float* __restrict__ Wv, const float* __restrict__ bv,
    short* __restrict__ qb, short* __restrict__ kb, short* __restrict__ vb)
{
  __shared__ __align__(16) short Wt[128 * 40];  // [ch][c], stride 40 (2-way free)
  __shared__ __align__(16) short Xt[64 * 40];   // [px][c]
  __shared__ __align__(16) short T[9216];       // epilogue tile
  const int tid = threadIdx.x;
  const int wv = tid >> 6;
  const int lane = tid & 63;
  const int t = lane & 15, q = lane >> 4;
  const int px0 = blockIdx.x * 64;
  const int which = blockIdx.y;
  const int b = blockIdx.z;
  const float* X    = (which == 0) ? src : tgt;
  const float* Wm   = (which == 0) ? Wq : (which == 1) ? Wk : Wv;
  const float* bias = (which == 0) ? bq : (which == 1) ? bk : bv;

  const f32x4 zf = {0.f, 0.f, 0.f, 0.f};
  f32x4 acc[2][4];
#pragma unroll
  for (int mt = 0; mt < 2; ++mt)
#pragma unroll
    for (int nt = 0; nt < 4; ++nt) acc[mt][nt] = zf;

  for (int kk = 0; kk < CC; kk += 32) {
    __syncthreads();
    // stage W tile: 128 ch x 32 c (f32 -> bf16)
#pragma unroll
    for (int u = 0; u < 4; ++u) {
      int e = tid + (u << 8);
      int row = e >> 3, cq = (e & 7) * 4;
      float4 w4 = *(const float4*)&Wm[row * CC + kk + cq];
      unsigned* dst = (unsigned*)(Wt + row * 40 + cq);
      dst[0] = pk2(w4.x, w4.y);
      dst[1] = pk2(w4.z, w4.w);
    }
    // stage X tile transposed: 32 c x 64 px -> Xt[px][c]
#pragma unroll
    for (int u = 0; u < 2; ++u) {
      int e = tid + (u << 8);
      int c = e >> 4, p4 = (e & 15) * 4;
      float4 xv = *(const float4*)&X[((size_t)b * CC + kk + c) * HW + px0 + p4];
      Xt[(p4 + 0) * 40 + c] = f2b(xv.x);
      Xt[(p4 + 1) * 40 + c] = f2b(xv.y);
      Xt[(p4 + 2) * 40 + c] = f2b(xv.z);
      Xt[(p4 + 3) * 40 + c] = f2b(xv.w);
    }
    __syncthreads();
    bf16x8 af[2], bfr[4];
#pragma unroll
    for (int mt = 0; mt < 2; ++mt)
      af[mt] = *(const bf16x8*)(Wt + (wv * 32 + mt * 16 + t) * 40 + q * 8);
#pragma unroll
    for (int nt = 0; nt < 4; ++nt)
      bfr[nt] = *(const bf16x8*)(Xt + (nt * 16 + t) * 40 + q * 8);
#pragma unroll
    for (int mt = 0; mt < 2; ++mt)
#pragma unroll
      for (int nt = 0; nt < 4; ++nt)
        acc[mt][nt] = __builtin_amdgcn_mfma_f32_16x16x32_bf16(
            af[mt], bfr[nt], acc[mt][nt], 0, 0, 0);
  }
  __syncthreads();
  // D mapping (verified idiom): ch = wv*32 + mt*16 + q*4 + r, px = nt*16 + t
  if (which < 2) {
    // T[px][ch], stride 136 -> coalesced (B,HW,128) store
#pragma unroll
    for (int mt = 0; mt < 2; ++mt) {
      int chb = wv * 32 + mt * 16 + q * 4;
#pragma unroll
      for (int r = 0; r < 4; ++r) {
        float bv_ = bias[chb + r];
#pragma unroll
        for (int nt = 0; nt < 4; ++nt)
          T[(nt * 16 + t) * 136 + chb + r] = f2b(acc[mt][nt][r] + bv_);
      }
    }
    __syncthreads();
    short* out = (which == 0) ? qb : kb;
    int p = tid >> 2, cq = (tid & 3) * 32;
    short* gdst = out + ((size_t)b * HW + px0 + p) * DD + cq;
#pragma unroll
    for (int e2 = 0; e2 < 4; ++e2)
      *(uint4*)(gdst + e2 * 8) = *(const uint4*)(T + p * 136 + cq + e2 * 8);
  } else {
    // T[ch][px], stride 72 -> coalesced (B,128,HW) store
#pragma unroll
    for (int mt = 0; mt < 2; ++mt) {
      int chb = wv * 32 + mt * 16 + q * 4;
#pragma unroll
      for (int r = 0; r < 4; ++r) {
        float bv_ = bias[chb + r];
#pragma unroll
        for (int nt = 0; nt < 4; ++nt)
          T[(chb + r) * 72 + nt * 16 + t] = f2b(acc[mt][nt][r] + bv_);
      }
    }
    __syncthreads();
    int ch = tid >> 1, pq = (tid & 1) * 32;
    short* gdst = vb + ((size_t)b * DD + ch) * HW + px0 + pq;
#pragma unroll
    for (int e2 = 0; e2 < 4; ++e2)
      *(uint4*)(gdst + e2 * 8) = *(const uint4*)(T + ch * 72 + pq + e2 * 8);
  }
}

// ---------------- K2: pass1 MFMA partial sums: rl[j] += sum_{i in range} exp(s[i,j])
// i-range split x4 across blockIdx.y for occupancy; rl pre-zeroed.
__global__ __launch_bounds__(256) void k_lsum2(
    const short* __restrict__ qb, const short* __restrict__ kb,
    float* __restrict__ rl)
{
  __shared__ float lred[4][64];
  const int tid = threadIdx.x;
  const int w = tid >> 6;
  const int lane = tid & 63;
  const int t = lane & 15, q = lane >> 4;
  const int j0 = blockIdx.x * 64;
  const int ibeg = blockIdx.y * 1024;
  const int b = blockIdx.z;
  const short* qbb = qb + (size_t)b * HW * DD;
  const short* kbb = kb + (size_t)b * HW * DD;

  bf16x8 Bq[4][4];
#pragma unroll
  for (int nt = 0; nt < 4; ++nt)
#pragma unroll
    for (int kk = 0; kk < 4; ++kk)
      Bq[nt][kk] = *(const bf16x8*)(qbb + (size_t)(j0 + nt * 16 + t) * DD + kk * 32 + q * 8);

  float racc[4] = {0.f, 0.f, 0.f, 0.f};
  const f32x4 zf = {0.f, 0.f, 0.f, 0.f};

  for (int i = ibeg + w * 16; i < ibeg + 1024; i += 64) {
    bf16x8 Ak[4];
#pragma unroll
    for (int kk = 0; kk < 4; ++kk)
      Ak[kk] = *(const bf16x8*)(kbb + (size_t)(i + t) * DD + kk * 32 + q * 8);
#pragma unroll
    for (int nt = 0; nt < 4; ++nt) {
      f32x4 d = zf;
#pragma unroll
      for (int kk = 0; kk < 4; ++kk)
        d = __builtin_amdgcn_mfma_f32_16x16x32_bf16(Ak[kk], Bq[nt][kk], d, 0, 0, 0);
      racc[nt] += __expf(d[0]) + __expf(d[1]) + __expf(d[2]) + __expf(d[3]);
    }
  }
#pragma unroll
  for (int nt = 0; nt < 4; ++nt) {
    float r = racc[nt];
    r += __shfl_xor(r, 16);
    r += __shfl_xor(r, 32);
    if (q == 0) lred[w][nt * 16 + t] = r;
  }
  __syncthreads();
  if (tid < 64) {
    float sum = lred[0][tid] + lred[1][tid] + lred[2][tid] + lred[3][tid];
    atomicAdd(&rl[(size_t)b * HW + j0 + tid], sum);
  }
}

// ---------------- K2b: vs[c][j] = bf16( vb[c][j] / l_j )   (B,128,HW)
__global__ __launch_bounds__(256) void k_vs(
    const short* __restrict__ vb, const float* __restrict__ rl,
    short* __restrict__ vs)
{
  int id4 = (blockIdx.x * 256 + threadIdx.x) * 4;
  int j = id4 & (HW - 1);
  int b = id4 >> 19;
  uint2 pv = *(const uint2*)(vb + id4);
  float f0 = __uint_as_float(pv.x << 16);
  float f1 = __uint_as_float(pv.x & 0xffff0000u);
  float f2 = __uint_as_float(pv.y << 16);
  float f3 = __uint_as_float(pv.y & 0xffff0000u);
  const float* rlb = rl + (size_t)b * HW + j;
  unsigned u0 = pk2(f0 / rlb[0], f1 / rlb[1]);
  unsigned u1 = pk2(f2 / rlb[2], f3 / rlb[3]);
  *(uint2*)(vs + id4) = make_uint2(u0, u1);
}

// ---------------- K3: pass2, R0 structure (LDS-P, b128 PV reads) +
//  (a) T14 async-STAGE: tile t+1's global loads issued before compute of t,
//      ds_write at next iteration's top (latency hides under S/exp/PV).
//  (b) P stride 76: breaks q/q+2 row aliasing on P-writes.
__global__ __launch_bounds__(256, 2) void k_attn2(
    const short* __restrict__ qb, const short* __restrict__ kb,
    const short* __restrict__ vs, float* __restrict__ ao)
{
  __shared__ __align__(16) short Qs[64 * 136];   // [j][c], stride 136 shorts
  __shared__ __align__(16) short Vss[128 * 72];  // [c][j], stride 72 shorts
  __shared__ __align__(16) short P[4][16][76];   // per-wave P tile, stride 76
  const int tid = threadIdx.x;
  const int w = tid >> 6;
  const int lane = tid & 63;
  const int t = lane & 15, q = lane >> 4;
  const int b = blockIdx.z;
  const int i0 = blockIdx.x * 64 + w * 16;
  const int jbeg = blockIdx.y * 2048, jend = jbeg + 2048;
  const short* qbb = qb + (size_t)b * HW * DD;
  const short* kbb = kb + (size_t)b * HW * DD;
  const short* vsb = vs + (size_t)b * DD * HW;
  const f32x4 zf = {0.f, 0.f, 0.f, 0.f};

  bf16x8 Ak[4];
#pragma unroll
  for (int kk = 0; kk < 4; ++kk)
    Ak[kk] = *(const bf16x8*)(kbb + (size_t)(i0 + t) * DD + kk * 32 + q * 8);

  f32x4 acc[8];
#pragma unroll
  for (int nt = 0; nt < 8; ++nt) acc[nt] = zf;

  // T14 prologue: prefetch tile jbeg into registers
  bf16x8 rq[4], rv[4];
#pragma unroll
  for (int r = 0; r < 4; ++r) {
    int e = tid + (r << 8);
    rq[r] = *(const bf16x8*)(qbb + (size_t)(jbeg + (e >> 4)) * DD + (e & 15) * 8);
    rv[r] = *(const bf16x8*)(vsb + (size_t)(e >> 3) * HW + jbeg + (e & 7) * 8);
  }

  for (int j = jbeg; j < jend; j += 64) {
    __syncthreads();   // prior iteration's LDS reads complete
#pragma unroll
    for (int r = 0; r < 4; ++r) {
      int e = tid + (r << 8);
      *(bf16x8*)(Qs + (e >> 4) * 136 + (e & 15) * 8) = rq[r];
      *(bf16x8*)(Vss + (e >> 3) * 72 + (e & 7) * 8) = rv[r];
    }
    __syncthreads();
    // issue next tile's global loads early; consumed at next iter's ds_write
    if (j + 64 < jend) {
#pragma unroll
      for (int r = 0; r < 4; ++r) {
        int e = tid + (r << 8);
        rq[r] = *(const bf16x8*)(qbb + (size_t)(j + 64 + (e >> 4)) * DD + (e & 15) * 8);
        rv[r] = *(const bf16x8*)(vsb + (size_t)(e >> 3) * HW + j + 64 + (e & 7) * 8);
      }
    }
    // S: sv[nt][r] = S[i0 + q*4 + r][j + nt*16 + t]
    f32x4 sv[4];
#pragma unroll
    for (int nt = 0; nt < 4; ++nt) sv[nt] = zf;
#pragma unroll
    for (int nt = 0; nt < 4; ++nt)
#pragma unroll
      for (int kk = 0; kk < 4; ++kk) {
        bf16x8 bq = *(const bf16x8*)(Qs + (nt * 16 + t) * 136 + kk * 32 + q * 8);
        sv[nt] = __builtin_amdgcn_mfma_f32_16x16x32_bf16(Ak[kk], bq, sv[nt], 0, 0, 0);
      }
    // P round-trip (per-wave, stride 76)
#pragma unroll
    for (int nt = 0; nt < 4; ++nt)
#pragma unroll
      for (int r = 0; r < 4; ++r)
        P[w][q * 4 + r][nt * 16 + t] = f2b(__expf(sv[nt][r]));
    bf16x8 ap[2];
#pragma unroll
    for (int ks = 0; ks < 2; ++ks) {
      bf16x4 lo = *(const bf16x4*)&P[w][t][ks * 32 + q * 8];
      bf16x4 hi = *(const bf16x4*)&P[w][t][ks * 32 + q * 8 + 4];
      ap[ks] = __builtin_shufflevector(lo, hi, 0, 1, 2, 3, 4, 5, 6, 7);
    }
    // PV: b128 Vss reads (R0 pattern)
#pragma unroll
    for (int nt = 0; nt < 8; ++nt)
#pragma unroll
      for (int ks = 0; ks < 2; ++ks) {
        bf16x8 bv = *(const bf16x8*)(Vss + (nt * 16 + t) * 72 + ks * 32 + q * 8);
        acc[nt] = __builtin_amdgcn_mfma_f32_16x16x32_bf16(ap[ks], bv, acc[nt], 0, 0, 0);
      }
  }
  float* aob = ao + (size_t)b * DD * HW;
#pragma unroll
  for (int nt = 0; nt < 8; ++nt)
#pragma unroll
    for (int r = 0; r < 4; ++r)
      atomicAdd(&aob[(size_t)(nt * 16 + t) * HW + i0 + q * 4 + r], acc[nt][r]);
}

// ---------------- K4: y = tgt + gamma*(Wp@ao + bp) -> Xn interior, ch [0,256)
// Xn layout: (B, 66, 66, 768) NHWC bf16 with a zeroed guard ring.
__global__ __launch_bounds__(256) void k_proj(
    const float* __restrict__ ao, const float* __restrict__ tgt,
    const float* __restrict__ Wp, const float* __restrict__ bp,
    const float* __restrict__ gamma, short* __restrict__ Xn)
{
  __shared__ float Wt[32][132];
  __shared__ float Xs[32][68];
  __shared__ float T[64][133];
  const int tid = threadIdx.x;
  const int tx = tid & 15, ty = tid >> 4;
  const int p0 = blockIdx.x * 64;
  const int ro = blockIdx.y * 128;
  const int b = blockIdx.z;
  const float g0 = gamma[0];

  float acc[8][4];
#pragma unroll
  for (int i = 0; i < 8; ++i)
#pragma unroll
    for (int j = 0; j < 4; ++j) acc[i][j] = 0.f;

  for (int kk = 0; kk < DD; kk += 32) {
    __syncthreads();
#pragma unroll
    for (int u = 0; u < 4; ++u) {
      int e = tid + 256 * u;
      int c4 = (e & 7) * 4, r = e >> 3;
      float w[4]; ld4(w, &Wp[(ro + r) * DD + kk + c4]);
      Wt[c4 + 0][r] = w[0]; Wt[c4 + 1][r] = w[1];
      Wt[c4 + 2][r] = w[2]; Wt[c4 + 3][r] = w[3];
    }
#pragma unroll
    for (int u = 0; u < 2; ++u) {
      int e = tid + 256 * u;
      int p4 = (e & 15) * 4, c = e >> 4;
      *(float4*)&Xs[c][p4] = *(const float4*)&ao[(b * DD + kk + c) * HW + p0 + p4];
    }
    __syncthreads();
#pragma unroll 4
    for (int c = 0; c < 32; ++c) {
      float wa[8], xb[4];
      ld4(wa, &Wt[c][ty * 8]); ld4(wa + 4, &Wt[c][ty * 8 + 4]);
      ld4(xb, &Xs[c][tx * 4]);
#pragma unroll
      for (int rr = 0; rr < 8; ++rr)
#pragma unroll
        for (int pp = 0; pp < 4; ++pp) acc[rr][pp] += wa[rr] * xb[pp];
    }
  }
#pragma unroll
  for (int rr = 0; rr < 8; ++rr) {
    int r = ro + ty * 8 + rr;
    int idx = (b * CC + r) * HW + p0 + tx * 4;
    float4 t4 = *(const float4*)&tgt[idx];
    float bpv = bp[r];
    T[tx * 4 + 0][ty * 8 + rr] = t4.x + g0 * (acc[rr][0] + bpv);
    T[tx * 4 + 1][ty * 8 + rr] = t4.y + g0 * (acc[rr][1] + bpv);
    T[tx * 4 + 2][ty * 8 + rr] = t4.z + g0 * (acc[rr][2] + bpv);
    T[tx * 4 + 3][ty * 8 + rr] = t4.w + g0 * (acc[rr][3] + bpv);
  }
  __syncthreads();
  {
    int p = tid >> 2, cq = (tid & 3) * 32;
    int h = p0 >> 6;
    unsigned* dst = (unsigned*)(Xn + ((((size_t)b * 66 + h + 1) * 66) + 1 + p) * 768 + ro + cq);
#pragma unroll
    for (int e = 0; e < 16; ++e)
      dst[e] = pk2(T[p][cq + 2 * e], T[p][cq + 2 * e + 1]);
  }
}

// ---------------- K4b: upsample prev into Xn interior, channels [256,768)
__global__ __launch_bounds__(256) void k_pack(
    const float* __restrict__ prev, short* __restrict__ Xn)
{
  __shared__ float tile[64][65];
  const int tid = threadIdx.x;
  const int h = blockIdx.x;
  const int ci0 = blockIdx.y * 64;
  const int b = blockIdx.z;

  {
    int w = tid & 63, r = tid >> 6;
    for (int cs = r; cs < 64; cs += 4)
      tile[cs][w] = prev[((size_t)b * 512 + ci0 + cs) * 1024 + (h >> 1) * 32 + (w >> 1)];
  }
  __syncthreads();
  {
    int ci = tid & 63, wq = tid >> 6;
    for (int ws2 = wq; ws2 < 64; ws2 += 4)
      Xn[((((size_t)b * 66 + h + 1) * 66) + 1 + ws2) * 768 + 256 + ci0 + ci] = f2b(tile[ci][ws2]);
  }
}

// ---------------- K4c: weight repack Wc(256,768,3,3) f32 -> Wb(256,9,768) bf16
__global__ __launch_bounds__(256) void k_wb(
    const float* __restrict__ Wc, short* __restrict__ Wb)
{
  int i = blockIdx.x * 256 + threadIdx.x;
  int o = i / 6912;
  int rem = i - o * 6912;
  int khw = rem / 768;
  int ci = rem - khw * 768;
  Wb[i] = f2b(Wc[(size_t)o * 6912 + ci * 9 + khw]);
}

// ---------------- K5: 3x3 conv, restructured implicit GEMM.
// Block tile: M=128 outch x N=128 px (2 h-rows), K=6912 at ci-step 32.
// 4 waves as 2m x 2n, each wave owns a 64x64 tile (square -> fewest LDS
// reads per MAC). X tile (4 input rows) staged ONCE per ci-chunk and
// reused across all 3 kh; W tile (3kw x 128cout x 32ci) re-staged per kh
// with T14 reg-prefetch (loads issued one compute-phase early).
// LDS strides 36 shorts (18 dwords) -> uniform bank spread on all patterns.
__global__ __launch_bounds__(256) void k_conv_mfma(
    const short* __restrict__ Xn,   // (B,66,66,768) bf16, guard ring zero
    const short* __restrict__ Wb,   // (256,9,768) bf16
    const float* __restrict__ bcw,
    short* __restrict__ cb)         // (B,256,4096) bf16
{
  __shared__ __align__(16) short smem[23328];  // W: [0,13824) ; X: [13824,23328)
  const int tid = threadIdx.x;
  const int wv = tid >> 6;
  const int lane = tid & 63;
  const int t = lane & 15, q = lane >> 4;
  const int wm = wv >> 1, wn = wv & 1;
  const int h0 = blockIdx.x * 2;      // output rows h0, h0+1
  const int m0 = blockIdx.y * 128;
  const int b = blockIdx.z;
  short* Wl = smem;                   // [384 = kw*128+cout][36]
  short* Xl = smem + 13824;           // [264 = tr*66+px][36]

  const f32x4 zf = {0.f, 0.f, 0.f, 0.f};
  f32x4 acc[4][4];
#pragma unroll
  for (int mt = 0; mt < 4; ++mt)
#pragma unroll
    for (int nt = 0; nt < 4; ++nt) acc[mt][nt] = zf;

  const short* xbase = Xn + ((size_t)b * 66 + h0) * 66 * 768;
  const short* wbase = Wb + (size_t)m0 * 6912;

  bf16x8 wr[6], xr[5];

#define LOADW(ci0, kh)                                                        \
  {                                                                           \
    _Pragma("unroll")                                                         \
    for (int r = 0; r < 6; ++r) {                                             \
      int e = tid + (r << 8);                                                 \
      int u = e & 3, row = e >> 2;                                            \
      int kw_ = row >> 7, cl = row & 127;                                     \
      wr[r] = *(const bf16x8*)(wbase + (size_t)cl * 6912 +                    \
                               ((kh) * 3 + kw_) * 768 + (ci0) + u * 8);       \
    }                                                                         \
  }
#define LOADX(ci0)                                                            \
  {                                                                           \
    _Pragma("unroll")                                                         \
    for (int r = 0; r < 5; ++r) {                                             \
      int e = tid + (r << 8);                                                 \
      if (e < 1056) {                                                         \
        int u = e & 3, prow = e >> 2;                                         \
        int tr = (prow * 993) >> 16;                                          \
        int rem = prow - tr * 66;                                             \
        xr[r] = *(const bf16x8*)(xbase + ((size_t)tr * 66 + rem) * 768 +      \
                                 (ci0) + u * 8);                              \
      }                                                                       \
    }                                                                         \
  }
#define WRITEW()                                                              \
  {                                                                           \
    _Pragma("unroll")                                                         \
    for (int r = 0; r < 6; ++r) {                                             \
      int e = tid + (r << 8);                                                 \
      int u = e & 3, row = e >> 2;                                            \
      *(bf16x8*)(Wl + row * 36 + u * 8) = wr[r];                              \
    }                                                                         \
  }
#define WRITEX()                                                              \
  {                                                                           \
    _Pragma("unroll")                                                         \
    for (int r = 0; r < 5; ++r) {                                             \
      int e = tid + (r << 8);                                                 \
      if (e < 1056) {                                                         \
        int u = e & 3, prow = e >> 2;                                         \
        *(bf16x8*)(Xl + prow * 36 + u * 8) = xr[r];                           \
      }                                                                       \
    }                                                                         \
  }
#define COMPUTE(kh)                                                           \
  {                                                                           \
    _Pragma("unroll")                                                         \
    for (int kw_ = 0; kw_ < 3; ++kw_) {                                       \
      bf16x8 af[4], bfr[4];                                                   \
      _Pragma("unroll")                                                       \
      for (int mt = 0; mt < 4; ++mt)                                          \
        af[mt] = *(const bf16x8*)(Wl +                                        \
            (kw_ * 128 + wm * 64 + mt * 16 + t) * 36 + q * 8);                \
      _Pragma("unroll")                                                       \
      for (int nt = 0; nt < 4; ++nt)                                          \
        bfr[nt] = *(const bf16x8*)(Xl +                                       \
            ((wn + (kh)) * 66 + nt * 16 + t + kw_) * 36 + q * 8);             \
      _Pragma("unroll")                                                       \
      for (int mt = 0; mt < 4; ++mt)                                          \
        _Pragma("unroll")                                                     \
        for (int nt = 0; nt < 4; ++nt)                                        \
          acc[mt][nt] = __builtin_amdgcn_mfma_f32_16x16x32_bf16(              \
              af[mt], bfr[nt], acc[mt][nt], 0, 0, 0);                         \
    }                                                                         \
  }

  LOADX(0);
  LOADW(0, 0);
  for (int ci0 = 0; ci0 < 768; ci0 += 32) {
    __syncthreads();          // previous compute's LDS reads complete
    WRITEX();
    WRITEW();
    __syncthreads();
    LOADW(ci0, 1);            // overlap with compute(0)
    COMPUTE(0);
    __syncthreads();
    WRITEW();
    __syncthreads();
    LOADW(ci0, 2);            // overlap with compute(1)
    COMPUTE(1);
    __syncthreads();
    WRITEW();
    __syncthreads();
    if (ci0 + 32 < 768) {     // overlap with compute(2)
      LOADW(ci0 + 32, 0);
      LOADX(ci0 + 32);
    }
    COMPUTE(2);
  }
#undef LOADW
#undef LOADX
#undef WRITEW
#undef WRITEX
#undef COMPUTE

  // D mapping: outch = m0 + wm*64 + mt*16 + q*4 + rr ; px = nt*16 + t ;
  // output row = h0 + wn (each wave owns one of the two rows)
#pragma unroll
  for (int mt = 0; mt < 4; ++mt) {
    int om = m0 + wm * 64 + mt * 16 + q * 4;
#pragma unroll
    for (int rr = 0; rr < 4; ++rr) {
      float bias = bcw[om + rr];
      short* orow = cb + ((size_t)b * CC + om + rr) * HW + (h0 + wn) * 64;
#pragma unroll
      for (int nt = 0; nt < 4; ++nt)
        orow[nt * 16 + t] = f2b(acc[mt][nt][rr] + bias);
    }
  }
}

// ---------------- K6: InstanceNorm (biased var, eps=1e-5) + ReLU; bf16 in, f32 out
__global__ __launch_bounds__(256) void k_inorm(
    const short* __restrict__ cb, float* __restrict__ out)
{
  __shared__ float buf[4096];
  __shared__ float red[8];
  const int tid = threadIdx.x;
  const int ch = blockIdx.x;
  const short* srcp = cb + (size_t)ch * HW;

  float s = 0.f, sq = 0.f;
#pragma unroll
  for (int u = 0; u < 2; ++u) {
    int sidx = u * 2048 + tid * 8;
    uint4 pk = *(const uint4*)(srcp + sidx);
    float f[8];
    f[0] = __uint_as_float(pk.x << 16); f[1] = __uint_as_float(pk.x & 0xffff0000u);
    f[2] = __uint_as_float(pk.y << 16); f[3] = __uint_as_float(pk.y & 0xffff0000u);
    f[4] = __uint_as_float(pk.z << 16); f[5] = __uint_as_float(pk.z & 0xffff0000u);
    f[6] = __uint_as_float(pk.w << 16); f[7] = __uint_as_float(pk.w & 0xffff0000u);
#pragma unroll
    for (int e = 0; e < 8; ++e) {
      buf[sidx + e] = f[e];
      s += f[e];
      sq += f[e] * f[e];
    }
  }
#pragma unroll
  for (int m = 32; m >= 1; m >>= 1) {
    s  += __shfl_xor(s, m, 64);
    sq += __shfl_xor(sq, m, 64);
  }
  if ((tid & 63) == 0) { red[tid >> 6] = s; red[4 + (tid >> 6)] = sq; }
  __syncthreads();
  if (tid == 0) {
    float S = red[0] + red[1] + red[2] + red[3];
    float Q = red[4] + red[5] + red[6] + red[7];
    float mean = S * (1.f / HW);
    float var = Q * (1.f / HW) - mean * mean;
    red[0] = mean;
    red[1] = rsqrtf(var + 1e-5f);
  }
  __syncthreads();
  const float mean = red[0], rs = red[1];
#pragma unroll
  for (int u = 0; u < 4; ++u) {
    int idx = u * 1024 + tid * 4;
    float4 v = *(const float4*)&buf[idx];
    float4 o4 = make_float4(fmaxf((v.x - mean) * rs, 0.f),
                            fmaxf((v.y - mean) * rs, 0.f),
                            fmaxf((v.z - mean) * rs, 0.f),
                            fmaxf((v.w - mean) * rs, 0.f));
    *(float4*)&out[(size_t)ch * HW + idx] = o4;
  }
}

extern "C" void kernel_launch(void* const* d_in, const int* in_sizes, int n_in,
                              void* d_out, int out_size, void* d_ws, size_t ws_size,
                              hipStream_t stream) {
  const float* src  = (const float*)d_in[0];
  const float* tgt  = (const float*)d_in[1];
  const float* prev = (const float*)d_in[2];
  const float* Wq = (const float*)d_in[3];  const float* bq = (const float*)d_in[4];
  const float* Wk = (const float*)d_in[5];  const float* bk = (const float*)d_in[6];
  const float* Wv = (const float*)d_in[7];  const float* bv = (const float*)d_in[8];
  const float* Wp = (const float*)d_in[9];  const float* bp = (const float*)d_in[10];
  const float* gamma = (const float*)d_in[11];
  const float* Wc = (const float*)d_in[12]; const float* bcw = (const float*)d_in[13];

  float* ws = (float*)d_ws;
  // float-unit offsets; lifetimes:
  short* qb = (short*)ws;                 // [0, 1048576)        dead after k_attn2
  short* kb = (short*)(ws + 1048576);     // [1048576, 2097152)  dead after k_attn2
  short* vb = (short*)(ws + 2097152);     // [2097152, 3145728)  dead after k_vs
  float* rl = ws + 3145728;               // [3145728, 3162112)  dead after k_vs
  short* vs = (short*)(ws + 3162112);     // [3162112, 4210688)  dead after k_attn2
  short* Xn = (short*)ws;                 // [0, 6690816)  (B,66,66,768) over qb/kb/vb/rl/vs
  float* ao = ws + 6690816;               // [6690816, 8787968)  zeroed before attn2
  short* cb = (short*)(ws + 6690816);     // over ao (ao dead after k_proj)
  short* Wb = (short*)(ws + 8787968);     // [8787968, 9672704)
  // high-water: 9,672,704 floats = 38.7 MB

  k_qkv_mfma<<<dim3(64, 3, BB), 256, 0, stream>>>(src, tgt, Wq, bq, Wk, bk, Wv, bv, qb, kb, vb);
  hipMemsetAsync(rl, 0, (size_t)BB * HW * 4, stream);
  k_lsum2<<<dim3(64, 4, BB), 256, 0, stream>>>(qb, kb, rl);
  k_vs   <<<dim3(2048),      256, 0, stream>>>(vb, rl, vs);
  hipMemsetAsync(ao, 0, (size_t)2097152 * 4, stream);
  k_attn2<<<dim3(64, 2, BB), 256, 0, stream>>>(qb, kb, vs, ao);
  // Xn overlaps qb/kb/vb/rl/vs -> zero only after k_attn2 (also zeroes guard ring)
  hipMemsetAsync(Xn, 0, (size_t)BB * 66 * 66 * 768 * 2, stream);
  k_proj <<<dim3(64, 2, BB), 256, 0, stream>>>(ao, tgt, Wp, bp, gamma, Xn);
  k_pack <<<dim3(64, 8, BB), 256, 0, stream>>>(prev, Xn);
  k_wb   <<<dim3(6912),      256, 0, stream>>>(Wc, Wb);
  k_conv_mfma<<<dim3(32, 2, BB), 256, 0, stream>>>(Xn, Wb, bcw, cb);
  k_inorm<<<dim3(1024),      256, 0, stream>>>(cb, (float*)d_out);
}

// Round 4
// 433.729 us; speedup vs baseline: 1.3571x; 1.3571x over previous
//
#include <hip/hip_runtime.h>
#include <hip/hip_bf16.h>

#define BB 4
#define CC 256
#define HW 4096
#define DD 128

typedef __attribute__((ext_vector_type(8))) short bf16x8;
typedef __attribute__((ext_vector_type(4))) short bf16x4;
typedef __attribute__((ext_vector_type(4))) float f32x4;

static __device__ __forceinline__ void ld4(float* dst, const float* src) {
  float4 t = *(const float4*)src;
  dst[0] = t.x; dst[1] = t.y; dst[2] = t.z; dst[3] = t.w;
}

// float -> bf16 (RNE) raw bits
static __device__ __forceinline__ short f2b(float f) {
  unsigned u = __float_as_uint(f);
  u += 0x7fffu + ((u >> 16) & 1u);
  return (short)(u >> 16);
}
static __device__ __forceinline__ unsigned pk2(float lo, float hi) {
  return (unsigned)(unsigned short)f2b(lo) | ((unsigned)(unsigned short)f2b(hi) << 16);
}

// ---------------- K1: q/k/v 1x1 conv as LDS-staged bf16 MFMA.
// Per (pxtile, which, b): GEMM W(128x256) @ X(256x64px).
// Outputs: q,k -> (B,HW,128) bf16 (pre-transposed for attention);
//          v   -> (B,128,HW) bf16.
__global__ __launch_bounds__(256) void k_qkv_mfma(
    const float* __restrict__ src, const float* __restrict__ tgt,
    const float* __restrict__ Wq, const float* __restrict__ bq,
    const float* __restrict__ Wk, const float* __restrict__ bk,
    const float* __restrict__ Wv, const float* __restrict__ bv,
    short* __restrict__ qb, short* __restrict__ kb, short* __restrict__ vb)
{
  __shared__ __align__(16) short Wt[128 * 40];  // [ch][c], stride 40 (2-way free)
  __shared__ __align__(16) short Xt[64 * 40];   // [px][c]
  __shared__ __align__(16) short T[9216];       // epilogue tile
  const int tid = threadIdx.x;
  const int wv = tid >> 6;
  const int lane = tid & 63;
  const int t = lane & 15, q = lane >> 4;
  const int px0 = blockIdx.x * 64;
  const int which = blockIdx.y;
  const int b = blockIdx.z;
  const float* X    = (which == 0) ? src : tgt;
  const float* Wm   = (which == 0) ? Wq : (which == 1) ? Wk : Wv;
  const float* bias = (which == 0) ? bq : (which == 1) ? bk : bv;

  const f32x4 zf = {0.f, 0.f, 0.f, 0.f};
  f32x4 acc[2][4];
#pragma unroll
  for (int mt = 0; mt < 2; ++mt)
#pragma unroll
    for (int nt = 0; nt < 4; ++nt) acc[mt][nt] = zf;

  for (int kk = 0; kk < CC; kk += 32) {
    __syncthreads();
    // stage W tile: 128 ch x 32 c (f32 -> bf16)
#pragma unroll
    for (int u = 0; u < 4; ++u) {
      int e = tid + (u << 8);
      int row = e >> 3, cq = (e & 7) * 4;
      float4 w4 = *(const float4*)&Wm[row * CC + kk + cq];
      unsigned* dst = (unsigned*)(Wt + row * 40 + cq);
      dst[0] = pk2(w4.x, w4.y);
      dst[1] = pk2(w4.z, w4.w);
    }
    // stage X tile transposed: 32 c x 64 px -> Xt[px][c]
#pragma unroll
    for (int u = 0; u < 2; ++u) {
      int e = tid + (u << 8);
      int c = e >> 4, p4 = (e & 15) * 4;
      float4 xv = *(const float4*)&X[((size_t)b * CC + kk + c) * HW + px0 + p4];
      Xt[(p4 + 0) * 40 + c] = f2b(xv.x);
      Xt[(p4 + 1) * 40 + c] = f2b(xv.y);
      Xt[(p4 + 2) * 40 + c] = f2b(xv.z);
      Xt[(p4 + 3) * 40 + c] = f2b(xv.w);
    }
    __syncthreads();
    bf16x8 af[2], bfr[4];
#pragma unroll
    for (int mt = 0; mt < 2; ++mt)
      af[mt] = *(const bf16x8*)(Wt + (wv * 32 + mt * 16 + t) * 40 + q * 8);
#pragma unroll
    for (int nt = 0; nt < 4; ++nt)
      bfr[nt] = *(const bf16x8*)(Xt + (nt * 16 + t) * 40 + q * 8);
#pragma unroll
    for (int mt = 0; mt < 2; ++mt)
#pragma unroll
      for (int nt = 0; nt < 4; ++nt)
        acc[mt][nt] = __builtin_amdgcn_mfma_f32_16x16x32_bf16(
            af[mt], bfr[nt], acc[mt][nt], 0, 0, 0);
  }
  __syncthreads();
  // D mapping (verified idiom): ch = wv*32 + mt*16 + q*4 + r, px = nt*16 + t
  if (which < 2) {
    // T[px][ch], stride 136 -> coalesced (B,HW,128) store
#pragma unroll
    for (int mt = 0; mt < 2; ++mt) {
      int chb = wv * 32 + mt * 16 + q * 4;
#pragma unroll
      for (int r = 0; r < 4; ++r) {
        float bv_ = bias[chb + r];
#pragma unroll
        for (int nt = 0; nt < 4; ++nt)
          T[(nt * 16 + t) * 136 + chb + r] = f2b(acc[mt][nt][r] + bv_);
      }
    }
    __syncthreads();
    short* out = (which == 0) ? qb : kb;
    int p = tid >> 2, cq = (tid & 3) * 32;
    short* gdst = out + ((size_t)b * HW + px0 + p) * DD + cq;
#pragma unroll
    for (int e2 = 0; e2 < 4; ++e2)
      *(uint4*)(gdst + e2 * 8) = *(const uint4*)(T + p * 136 + cq + e2 * 8);
  } else {
    // T[ch][px], stride 72 -> coalesced (B,128,HW) store
#pragma unroll
    for (int mt = 0; mt < 2; ++mt) {
      int chb = wv * 32 + mt * 16 + q * 4;
#pragma unroll
      for (int r = 0; r < 4; ++r) {
        float bv_ = bias[chb + r];
#pragma unroll
        for (int nt = 0; nt < 4; ++nt)
          T[(chb + r) * 72 + nt * 16 + t] = f2b(acc[mt][nt][r] + bv_);
      }
    }
    __syncthreads();
    int ch = tid >> 1, pq = (tid & 1) * 32;
    short* gdst = vb + ((size_t)b * DD + ch) * HW + px0 + pq;
#pragma unroll
    for (int e2 = 0; e2 < 4; ++e2)
      *(uint4*)(gdst + e2 * 8) = *(const uint4*)(T + ch * 72 + pq + e2 * 8);
  }
}

// ---------------- K2: pass1 MFMA partial sums: rl[j] += sum_{i in range} exp(s[i,j])
// i-range split x4 across blockIdx.y for occupancy; rl pre-zeroed.
__global__ __launch_bounds__(256) void k_lsum2(
    const short* __restrict__ qb, const short* __restrict__ kb,
    float* __restrict__ rl)
{
  __shared__ float lred[4][64];
  const int tid = threadIdx.x;
  const int w = tid >> 6;
  const int lane = tid & 63;
  const int t = lane & 15, q = lane >> 4;
  const int j0 = blockIdx.x * 64;
  const int ibeg = blockIdx.y * 1024;
  const int b = blockIdx.z;
  const short* qbb = qb + (size_t)b * HW * DD;
  const short* kbb = kb + (size_t)b * HW * DD;

  bf16x8 Bq[4][4];
#pragma unroll
  for (int nt = 0; nt < 4; ++nt)
#pragma unroll
    for (int kk = 0; kk < 4; ++kk)
      Bq[nt][kk] = *(const bf16x8*)(qbb + (size_t)(j0 + nt * 16 + t) * DD + kk * 32 + q * 8);

  float racc[4] = {0.f, 0.f, 0.f, 0.f};
  const f32x4 zf = {0.f, 0.f, 0.f, 0.f};

  for (int i = ibeg + w * 16; i < ibeg + 1024; i += 64) {
    bf16x8 Ak[4];
#pragma unroll
    for (int kk = 0; kk < 4; ++kk)
      Ak[kk] = *(const bf16x8*)(kbb + (size_t)(i + t) * DD + kk * 32 + q * 8);
#pragma unroll
    for (int nt = 0; nt < 4; ++nt) {
      f32x4 d = zf;
#pragma unroll
      for (int kk = 0; kk < 4; ++kk)
        d = __builtin_amdgcn_mfma_f32_16x16x32_bf16(Ak[kk], Bq[nt][kk], d, 0, 0, 0);
      racc[nt] += __expf(d[0]) + __expf(d[1]) + __expf(d[2]) + __expf(d[3]);
    }
  }
#pragma unroll
  for (int nt = 0; nt < 4; ++nt) {
    float r = racc[nt];
    r += __shfl_xor(r, 16);
    r += __shfl_xor(r, 32);
    if (q == 0) lred[w][nt * 16 + t] = r;
  }
  __syncthreads();
  if (tid < 64) {
    float sum = lred[0][tid] + lred[1][tid] + lred[2][tid] + lred[3][tid];
    atomicAdd(&rl[(size_t)b * HW + j0 + tid], sum);
  }
}

// ---------------- K2b: vs[c][j] = bf16( vb[c][j] / l_j )   (B,128,HW)
__global__ __launch_bounds__(256) void k_vs(
    const short* __restrict__ vb, const float* __restrict__ rl,
    short* __restrict__ vs)
{
  int id4 = (blockIdx.x * 256 + threadIdx.x) * 4;
  int j = id4 & (HW - 1);
  int b = id4 >> 19;
  uint2 pv = *(const uint2*)(vb + id4);
  float f0 = __uint_as_float(pv.x << 16);
  float f1 = __uint_as_float(pv.x & 0xffff0000u);
  float f2 = __uint_as_float(pv.y << 16);
  float f3 = __uint_as_float(pv.y & 0xffff0000u);
  const float* rlb = rl + (size_t)b * HW + j;
  unsigned u0 = pk2(f0 / rlb[0], f1 / rlb[1]);
  unsigned u1 = pk2(f2 / rlb[2], f3 / rlb[3]);
  *(uint2*)(vs + id4) = make_uint2(u0, u1);
}

// ---------------- K3: pass2, R0 structure (LDS-P, b128 PV reads) +
//  (a) T14 async-STAGE: tile t+1's global loads issued before compute of t,
//      ds_write at next iteration's top (latency hides under S/exp/PV).
//  (b) P stride 76: breaks q/q+2 row aliasing on P-writes.
__global__ __launch_bounds__(256, 2) void k_attn2(
    const short* __restrict__ qb, const short* __restrict__ kb,
    const short* __restrict__ vs, float* __restrict__ ao)
{
  __shared__ __align__(16) short Qs[64 * 136];   // [j][c], stride 136 shorts
  __shared__ __align__(16) short Vss[128 * 72];  // [c][j], stride 72 shorts
  __shared__ __align__(16) short P[4][16][76];   // per-wave P tile, stride 76
  const int tid = threadIdx.x;
  const int w = tid >> 6;
  const int lane = tid & 63;
  const int t = lane & 15, q = lane >> 4;
  const int b = blockIdx.z;
  const int i0 = blockIdx.x * 64 + w * 16;
  const int jbeg = blockIdx.y * 2048, jend = jbeg + 2048;
  const short* qbb = qb + (size_t)b * HW * DD;
  const short* kbb = kb + (size_t)b * HW * DD;
  const short* vsb = vs + (size_t)b * DD * HW;
  const f32x4 zf = {0.f, 0.f, 0.f, 0.f};

  bf16x8 Ak[4];
#pragma unroll
  for (int kk = 0; kk < 4; ++kk)
    Ak[kk] = *(const bf16x8*)(kbb + (size_t)(i0 + t) * DD + kk * 32 + q * 8);

  f32x4 acc[8];
#pragma unroll
  for (int nt = 0; nt < 8; ++nt) acc[nt] = zf;

  // T14 prologue: prefetch tile jbeg into registers
  bf16x8 rq[4], rv[4];
#pragma unroll
  for (int r = 0; r < 4; ++r) {
    int e = tid + (r << 8);
    rq[r] = *(const bf16x8*)(qbb + (size_t)(jbeg + (e >> 4)) * DD + (e & 15) * 8);
    rv[r] = *(const bf16x8*)(vsb + (size_t)(e >> 3) * HW + jbeg + (e & 7) * 8);
  }

  for (int j = jbeg; j < jend; j += 64) {
    __syncthreads();   // prior iteration's LDS reads complete
#pragma unroll
    for (int r = 0; r < 4; ++r) {
      int e = tid + (r << 8);
      *(bf16x8*)(Qs + (e >> 4) * 136 + (e & 15) * 8) = rq[r];
      *(bf16x8*)(Vss + (e >> 3) * 72 + (e & 7) * 8) = rv[r];
    }
    __syncthreads();
    // issue next tile's global loads early; consumed at next iter's ds_write
    if (j + 64 < jend) {
#pragma unroll
      for (int r = 0; r < 4; ++r) {
        int e = tid + (r << 8);
        rq[r] = *(const bf16x8*)(qbb + (size_t)(j + 64 + (e >> 4)) * DD + (e & 15) * 8);
        rv[r] = *(const bf16x8*)(vsb + (size_t)(e >> 3) * HW + j + 64 + (e & 7) * 8);
      }
    }
    // S: sv[nt][r] = S[i0 + q*4 + r][j + nt*16 + t]
    f32x4 sv[4];
#pragma unroll
    for (int nt = 0; nt < 4; ++nt) sv[nt] = zf;
#pragma unroll
    for (int nt = 0; nt < 4; ++nt)
#pragma unroll
      for (int kk = 0; kk < 4; ++kk) {
        bf16x8 bq = *(const bf16x8*)(Qs + (nt * 16 + t) * 136 + kk * 32 + q * 8);
        sv[nt] = __builtin_amdgcn_mfma_f32_16x16x32_bf16(Ak[kk], bq, sv[nt], 0, 0, 0);
      }
    // P round-trip (per-wave, stride 76)
#pragma unroll
    for (int nt = 0; nt < 4; ++nt)
#pragma unroll
      for (int r = 0; r < 4; ++r)
        P[w][q * 4 + r][nt * 16 + t] = f2b(__expf(sv[nt][r]));
    bf16x8 ap[2];
#pragma unroll
    for (int ks = 0; ks < 2; ++ks) {
      bf16x4 lo = *(const bf16x4*)&P[w][t][ks * 32 + q * 8];
      bf16x4 hi = *(const bf16x4*)&P[w][t][ks * 32 + q * 8 + 4];
      ap[ks] = __builtin_shufflevector(lo, hi, 0, 1, 2, 3, 4, 5, 6, 7);
    }
    // PV: b128 Vss reads (R0 pattern)
#pragma unroll
    for (int nt = 0; nt < 8; ++nt)
#pragma unroll
      for (int ks = 0; ks < 2; ++ks) {
        bf16x8 bv = *(const bf16x8*)(Vss + (nt * 16 + t) * 72 + ks * 32 + q * 8);
        acc[nt] = __builtin_amdgcn_mfma_f32_16x16x32_bf16(ap[ks], bv, acc[nt], 0, 0, 0);
      }
  }
  float* aob = ao + (size_t)b * DD * HW;
#pragma unroll
  for (int nt = 0; nt < 8; ++nt)
#pragma unroll
    for (int r = 0; r < 4; ++r)
      atomicAdd(&aob[(size_t)(nt * 16 + t) * HW + i0 + q * 4 + r], acc[nt][r]);
}

// ---------------- K4: y = tgt + gamma*(Wp@ao + bp) -> Xn interior, ch [0,256)
// Xn layout: (B, 66, 66, 768) NHWC bf16 with a zeroed guard ring.
__global__ __launch_bounds__(256) void k_proj(
    const float* __restrict__ ao, const float* __restrict__ tgt,
    const float* __restrict__ Wp, const float* __restrict__ bp,
    const float* __restrict__ gamma, short* __restrict__ Xn)
{
  __shared__ float Wt[32][132];
  __shared__ float Xs[32][68];
  __shared__ float T[64][133];
  const int tid = threadIdx.x;
  const int tx = tid & 15, ty = tid >> 4;
  const int p0 = blockIdx.x * 64;
  const int ro = blockIdx.y * 128;
  const int b = blockIdx.z;
  const float g0 = gamma[0];

  float acc[8][4];
#pragma unroll
  for (int i = 0; i < 8; ++i)
#pragma unroll
    for (int j = 0; j < 4; ++j) acc[i][j] = 0.f;

  for (int kk = 0; kk < DD; kk += 32) {
    __syncthreads();
#pragma unroll
    for (int u = 0; u < 4; ++u) {
      int e = tid + 256 * u;
      int c4 = (e & 7) * 4, r = e >> 3;
      float w[4]; ld4(w, &Wp[(ro + r) * DD + kk + c4]);
      Wt[c4 + 0][r] = w[0]; Wt[c4 + 1][r] = w[1];
      Wt[c4 + 2][r] = w[2]; Wt[c4 + 3][r] = w[3];
    }
#pragma unroll
    for (int u = 0; u < 2; ++u) {
      int e = tid + 256 * u;
      int p4 = (e & 15) * 4, c = e >> 4;
      *(float4*)&Xs[c][p4] = *(const float4*)&ao[(b * DD + kk + c) * HW + p0 + p4];
    }
    __syncthreads();
#pragma unroll 4
    for (int c = 0; c < 32; ++c) {
      float wa[8], xb[4];
      ld4(wa, &Wt[c][ty * 8]); ld4(wa + 4, &Wt[c][ty * 8 + 4]);
      ld4(xb, &Xs[c][tx * 4]);
#pragma unroll
      for (int rr = 0; rr < 8; ++rr)
#pragma unroll
        for (int pp = 0; pp < 4; ++pp) acc[rr][pp] += wa[rr] * xb[pp];
    }
  }
#pragma unroll
  for (int rr = 0; rr < 8; ++rr) {
    int r = ro + ty * 8 + rr;
    int idx = (b * CC + r) * HW + p0 + tx * 4;
    float4 t4 = *(const float4*)&tgt[idx];
    float bpv = bp[r];
    T[tx * 4 + 0][ty * 8 + rr] = t4.x + g0 * (acc[rr][0] + bpv);
    T[tx * 4 + 1][ty * 8 + rr] = t4.y + g0 * (acc[rr][1] + bpv);
    T[tx * 4 + 2][ty * 8 + rr] = t4.z + g0 * (acc[rr][2] + bpv);
    T[tx * 4 + 3][ty * 8 + rr] = t4.w + g0 * (acc[rr][3] + bpv);
  }
  __syncthreads();
  {
    int p = tid >> 2, cq = (tid & 3) * 32;
    int h = p0 >> 6;
    unsigned* dst = (unsigned*)(Xn + ((((size_t)b * 66 + h + 1) * 66) + 1 + p) * 768 + ro + cq);
#pragma unroll
    for (int e = 0; e < 16; ++e)
      dst[e] = pk2(T[p][cq + 2 * e], T[p][cq + 2 * e + 1]);
  }
}

// ---------------- K4b: upsample prev into Xn interior, channels [256,768)
__global__ __launch_bounds__(256) void k_pack(
    const float* __restrict__ prev, short* __restrict__ Xn)
{
  __shared__ float tile[64][65];
  const int tid = threadIdx.x;
  const int h = blockIdx.x;
  const int ci0 = blockIdx.y * 64;
  const int b = blockIdx.z;

  {
    int w = tid & 63, r = tid >> 6;
    for (int cs = r; cs < 64; cs += 4)
      tile[cs][w] = prev[((size_t)b * 512 + ci0 + cs) * 1024 + (h >> 1) * 32 + (w >> 1)];
  }
  __syncthreads();
  {
    int ci = tid & 63, wq = tid >> 6;
    for (int ws2 = wq; ws2 < 64; ws2 += 4)
      Xn[((((size_t)b * 66 + h + 1) * 66) + 1 + ws2) * 768 + 256 + ci0 + ci] = f2b(tile[ci][ws2]);
  }
}

// ---------------- K4c: weight repack Wc(256,768,3,3) f32 -> Wb(256,9,768) bf16
__global__ __launch_bounds__(256) void k_wb(
    const float* __restrict__ Wc, short* __restrict__ Wb)
{
  int i = blockIdx.x * 256 + threadIdx.x;
  int o = i / 6912;
  int rem = i - o * 6912;
  int khw = rem / 768;
  int ci = rem - khw * 768;
  Wb[i] = f2b(Wc[(size_t)o * 6912 + ci * 9 + khw]);
}

// ---------------- K5: 3x3 conv implicit GEMM, R2 skeleton (512 blocks, 2/CU)
// with the W LDS round-trip ELIMINATED: MFMA A-fragments load directly from
// global Wb to registers (per-lane layout matches the fragment: 4-lane
// q-groups read contiguous 64B, L2-resident). W regs double-buffered
// (afA/afB, prefetched one stage ahead). X stays LDS-staged, now
// double-buffered (2 x 9.5 KB) -> ONE barrier per stage (36 total).
__global__ __launch_bounds__(256, 2) void k_conv_mfma(
    const short* __restrict__ Xn,   // (B,66,66,768) bf16, guard ring zero
    const short* __restrict__ Wb,   // (256,9,768) bf16
    const float* __restrict__ bcw,
    short* __restrict__ cb)         // (B,256,4096) bf16
{
  __shared__ __align__(16) short Xl[2][4752];  // [66 rows][72 stride] x2
  const int tid = threadIdx.x;
  const int wv = tid >> 6;
  const int lane = tid & 63;
  const int t = lane & 15, q = lane >> 4;
  const int h = blockIdx.x;
  const int m0 = blockIdx.y * 128;
  const int b = blockIdx.z;

  const f32x4 zf = {0.f, 0.f, 0.f, 0.f};
  f32x4 acc[2][4];
#pragma unroll
  for (int mt = 0; mt < 2; ++mt)
#pragma unroll
    for (int nt = 0; nt < 4; ++nt) acc[mt][nt] = zf;

  const short* xbase = Xn + ((size_t)b * 66 + h) * 66 * 768;
  // per-lane W base: cout = m0 + wv*32 (+mt*16) + t ; ci-part q*8
  const short* wlane = Wb + (size_t)(m0 + wv * 32 + t) * 6912 + q * 8;

  // stage s = kh*12 + ci0/64, s in [0,36)
#define LOADAF(dst, s_)                                                       \
  {                                                                           \
    int s__ = (s_) < 36 ? (s_) : 35;                                          \
    int kh_ = s__ / 12, ci_ = (s__ - kh_ * 12) * 64;                          \
    _Pragma("unroll")                                                         \
    for (int kw_ = 0; kw_ < 3; ++kw_)                                         \
      _Pragma("unroll")                                                       \
      for (int kk_ = 0; kk_ < 2; ++kk_)                                       \
        _Pragma("unroll")                                                     \
        for (int mt_ = 0; mt_ < 2; ++mt_)                                     \
          dst[kw_ * 4 + kk_ * 2 + mt_] = *(const bf16x8*)(wlane +             \
              (size_t)mt_ * 16 * 6912 + (kh_ * 3 + kw_) * 768 + ci_ +         \
              kk_ * 32);                                                      \
  }
#define LOADXR(dst, s_)                                                       \
  {                                                                           \
    int s__ = (s_) < 36 ? (s_) : 35;                                          \
    int kh_ = s__ / 12, ci_ = (s__ - kh_ * 12) * 64;                          \
    const short* xsrc_ = xbase + (size_t)kh_ * 66 * 768 + ci_;                \
    _Pragma("unroll")                                                         \
    for (int r = 0; r < 3; ++r) {                                             \
      int e = tid + (r << 8);                                                 \
      if (e < 528) {                                                          \
        int u = e & 7, px = e >> 3;                                           \
        dst[r] = *(const bf16x8*)(xsrc_ + (size_t)px * 768 + u * 8);          \
      }                                                                       \
    }                                                                         \
  }
#define WRITEXB(buf, srcv)                                                    \
  {                                                                           \
    _Pragma("unroll")                                                         \
    for (int r = 0; r < 3; ++r) {                                             \
      int e = tid + (r << 8);                                                 \
      if (e < 528) {                                                          \
        int u = e & 7, px = e >> 3;                                           \
        *(bf16x8*)((buf) + px * 72 + u * 8) = srcv[r];                        \
      }                                                                       \
    }                                                                         \
  }
#define COMPUTE(buf, af)                                                      \
  {                                                                           \
    _Pragma("unroll")                                                         \
    for (int kw_ = 0; kw_ < 3; ++kw_) {                                       \
      bf16x8 bfr[4][2];                                                       \
      _Pragma("unroll")                                                       \
      for (int nt = 0; nt < 4; ++nt)                                          \
        _Pragma("unroll")                                                     \
        for (int kk_ = 0; kk_ < 2; ++kk_)                                     \
          bfr[nt][kk_] = *(const bf16x8*)((buf) +                             \
              (nt * 16 + t + kw_) * 72 + kk_ * 32 + q * 8);                   \
      _Pragma("unroll")                                                       \
      for (int kk_ = 0; kk_ < 2; ++kk_)                                       \
        _Pragma("unroll")                                                     \
        for (int mt_ = 0; mt_ < 2; ++mt_)                                     \
          _Pragma("unroll")                                                   \
          for (int nt = 0; nt < 4; ++nt)                                      \
            acc[mt_][nt] = __builtin_amdgcn_mfma_f32_16x16x32_bf16(           \
                af[kw_ * 4 + kk_ * 2 + mt_], bfr[nt][kk_], acc[mt_][nt],      \
                0, 0, 0);                                                     \
    }                                                                         \
  }

  bf16x8 afA[12], afB[12], xrW[3], xrW2[3];
  // prologue: X(0) -> buf0 ; X(1) loaded for stage0's write ; af(0) in regs
  LOADXR(xrW, 0);
  LOADAF(afA, 0);
  WRITEXB(Xl[0], xrW);
  LOADXR(xrW, 1);

  for (int s = 0; s < 36; s += 2) {
    __syncthreads();            // buf0 ready; prior readers of buf1 done
    WRITEXB(Xl[1], xrW);        // X(s+1)
    LOADXR(xrW2, s + 2);
    LOADAF(afB, s + 1);
    COMPUTE(Xl[0], afA);        // stage s
    __syncthreads();            // buf1 ready; readers of buf0 done
    WRITEXB(Xl[0], xrW2);       // X(s+2)
    LOADXR(xrW, s + 3);
    LOADAF(afA, s + 2);
    COMPUTE(Xl[1], afB);        // stage s+1
  }
#undef LOADAF
#undef LOADXR
#undef WRITEXB
#undef COMPUTE

  // D mapping: outch = m0 + wv*32 + mt*16 + q*4 + rr ; px = nt*16 + t
#pragma unroll
  for (int mt = 0; mt < 2; ++mt) {
    int om = m0 + wv * 32 + mt * 16 + q * 4;
#pragma unroll
    for (int rr = 0; rr < 4; ++rr) {
      float bias = bcw[om + rr];
      short* orow = cb + ((size_t)b * CC + om + rr) * HW + h * 64;
#pragma unroll
      for (int nt = 0; nt < 4; ++nt)
        orow[nt * 16 + t] = f2b(acc[mt][nt][rr] + bias);
    }
  }
}

// ---------------- K6: InstanceNorm (biased var, eps=1e-5) + ReLU; bf16 in, f32 out
__global__ __launch_bounds__(256) void k_inorm(
    const short* __restrict__ cb, float* __restrict__ out)
{
  __shared__ float buf[4096];
  __shared__ float red[8];
  const int tid = threadIdx.x;
  const int ch = blockIdx.x;
  const short* srcp = cb + (size_t)ch * HW;

  float s = 0.f, sq = 0.f;
#pragma unroll
  for (int u = 0; u < 2; ++u) {
    int sidx = u * 2048 + tid * 8;
    uint4 pk = *(const uint4*)(srcp + sidx);
    float f[8];
    f[0] = __uint_as_float(pk.x << 16); f[1] = __uint_as_float(pk.x & 0xffff0000u);
    f[2] = __uint_as_float(pk.y << 16); f[3] = __uint_as_float(pk.y & 0xffff0000u);
    f[4] = __uint_as_float(pk.z << 16); f[5] = __uint_as_float(pk.z & 0xffff0000u);
    f[6] = __uint_as_float(pk.w << 16); f[7] = __uint_as_float(pk.w & 0xffff0000u);
#pragma unroll
    for (int e = 0; e < 8; ++e) {
      buf[sidx + e] = f[e];
      s += f[e];
      sq += f[e] * f[e];
    }
  }
#pragma unroll
  for (int m = 32; m >= 1; m >>= 1) {
    s  += __shfl_xor(s, m, 64);
    sq += __shfl_xor(sq, m, 64);
  }
  if ((tid & 63) == 0) { red[tid >> 6] = s; red[4 + (tid >> 6)] = sq; }
  __syncthreads();
  if (tid == 0) {
    float S = red[0] + red[1] + red[2] + red[3];
    float Q = red[4] + red[5] + red[6] + red[7];
    float mean = S * (1.f / HW);
    float var = Q * (1.f / HW) - mean * mean;
    red[0] = mean;
    red[1] = rsqrtf(var + 1e-5f);
  }
  __syncthreads();
  const float mean = red[0], rs = red[1];
#pragma unroll
  for (int u = 0; u < 4; ++u) {
    int idx = u * 1024 + tid * 4;
    float4 v = *(const float4*)&buf[idx];
    float4 o4 = make_float4(fmaxf((v.x - mean) * rs, 0.f),
                            fmaxf((v.y - mean) * rs, 0.f),
                            fmaxf((v.z - mean) * rs, 0.f),
                            fmaxf((v.w - mean) * rs, 0.f));
    *(float4*)&out[(size_t)ch * HW + idx] = o4;
  }
}

extern "C" void kernel_launch(void* const* d_in, const int* in_sizes, int n_in,
                              void* d_out, int out_size, void* d_ws, size_t ws_size,
                              hipStream_t stream) {
  const float* src  = (const float*)d_in[0];
  const float* tgt  = (const float*)d_in[1];
  const float* prev = (const float*)d_in[2];
  const float* Wq = (const float*)d_in[3];  const float* bq = (const float*)d_in[4];
  const float* Wk = (const float*)d_in[5];  const float* bk = (const float*)d_in[6];
  const float* Wv = (const float*)d_in[7];  const float* bv = (const float*)d_in[8];
  const float* Wp = (const float*)d_in[9];  const float* bp = (const float*)d_in[10];
  const float* gamma = (const float*)d_in[11];
  const float* Wc = (const float*)d_in[12]; const float* bcw = (const float*)d_in[13];

  float* ws = (float*)d_ws;
  // float-unit offsets; lifetimes:
  short* qb = (short*)ws;                 // [0, 1048576)        dead after k_attn2
  short* kb = (short*)(ws + 1048576);     // [1048576, 2097152)  dead after k_attn2
  short* vb = (short*)(ws + 2097152);     // [2097152, 3145728)  dead after k_vs
  float* rl = ws + 3145728;               // [3145728, 3162112)  dead after k_vs
  short* vs = (short*)(ws + 3162112);     // [3162112, 4210688)  dead after k_attn2
  short* Xn = (short*)ws;                 // [0, 6690816)  (B,66,66,768) over qb/kb/vb/rl/vs
  float* ao = ws + 6690816;               // [6690816, 8787968)  zeroed before attn2
  short* cb = (short*)(ws + 6690816);     // over ao (ao dead after k_proj)
  short* Wb = (short*)(ws + 8787968);     // [8787968, 9672704)
  // high-water: 9,672,704 floats = 38.7 MB

  k_qkv_mfma<<<dim3(64, 3, BB), 256, 0, stream>>>(src, tgt, Wq, bq, Wk, bk, Wv, bv, qb, kb, vb);
  hipMemsetAsync(rl, 0, (size_t)BB * HW * 4, stream);
  k_lsum2<<<dim3(64, 4, BB), 256, 0, stream>>>(qb, kb, rl);
  k_vs   <<<dim3(2048),      256, 0, stream>>>(vb, rl, vs);
  hipMemsetAsync(ao, 0, (size_t)2097152 * 4, stream);
  k_attn2<<<dim3(64, 2, BB), 256, 0, stream>>>(qb, kb, vs, ao);
  // Xn overlaps qb/kb/vb/rl/vs -> zero only after k_attn2 (also zeroes guard ring)
  hipMemsetAsync(Xn, 0, (size_t)BB * 66 * 66 * 768 * 2, stream);
  k_proj <<<dim3(64, 2, BB), 256, 0, stream>>>(ao, tgt, Wp, bp, gamma, Xn);
  k_pack <<<dim3(64, 8, BB), 256, 0, stream>>>(prev, Xn);
  k_wb   <<<dim3(6912),      256, 0, stream>>>(Wc, Wb);
  k_conv_mfma<<<dim3(64, 2, BB), 256, 0, stream>>>(Xn, Wb, bcw, cb);
  k_inorm<<<dim3(1024),      256, 0, stream>>>(cb, (float*)d_out);
}

// Round 5
// 382.201 us; speedup vs baseline: 1.5401x; 1.1348x over previous
//
#include <hip/hip_runtime.h>
#include <hip/hip_bf16.h>

#define BB 4
#define CC 256
#define HW 4096
#define DD 128

typedef __attribute__((ext_vector_type(8))) short bf16x8;
typedef __attribute__((ext_vector_type(4))) short bf16x4;
typedef __attribute__((ext_vector_type(4))) float f32x4;

static __device__ __forceinline__ void ld4(float* dst, const float* src) {
  float4 t = *(const float4*)src;
  dst[0] = t.x; dst[1] = t.y; dst[2] = t.z; dst[3] = t.w;
}

// float -> bf16 (RNE) raw bits
static __device__ __forceinline__ short f2b(float f) {
  unsigned u = __float_as_uint(f);
  u += 0x7fffu + ((u >> 16) & 1u);
  return (short)(u >> 16);
}
static __device__ __forceinline__ unsigned pk2(float lo, float hi) {
  return (unsigned)(unsigned short)f2b(lo) | ((unsigned)(unsigned short)f2b(hi) << 16);
}

// async global->LDS DMA, 16B per lane; LDS dest must be linear in lane order
static __device__ __forceinline__ void gl16(const short* g, short* l) {
  __builtin_amdgcn_global_load_lds(
      (const __attribute__((address_space(1))) unsigned*)g,
      (__attribute__((address_space(3))) unsigned*)l, 16, 0, 0);
}

// ---------------- K1: q/k/v 1x1 conv as LDS-staged bf16 MFMA.
// Per (pxtile, which, b): GEMM W(128x256) @ X(256x64px).
// Outputs: q,k -> (B,HW,128) bf16 (pre-transposed for attention);
//          v   -> (B,128,HW) bf16.
__global__ __launch_bounds__(256) void k_qkv_mfma(
    const float* __restrict__ src, const float* __restrict__ tgt,
    const float* __restrict__ Wq, const float* __restrict__ bq,
    const float* __restrict__ Wk, const float* __restrict__ bk,
    const float* __restrict__ Wv, const float* __restrict__ bv,
    short* __restrict__ qb, short* __restrict__ kb, short* __restrict__ vb)
{
  __shared__ __align__(16) short Wt[128 * 40];  // [ch][c], stride 40 (2-way free)
  __shared__ __align__(16) short Xt[64 * 40];   // [px][c]
  __shared__ __align__(16) short T[9216];       // epilogue tile
  const int tid = threadIdx.x;
  const int wv = tid >> 6;
  const int lane = tid & 63;
  const int t = lane & 15, q = lane >> 4;
  const int px0 = blockIdx.x * 64;
  const int which = blockIdx.y;
  const int b = blockIdx.z;
  const float* X    = (which == 0) ? src : tgt;
  const float* Wm   = (which == 0) ? Wq : (which == 1) ? Wk : Wv;
  const float* bias = (which == 0) ? bq : (which == 1) ? bk : bv;

  const f32x4 zf = {0.f, 0.f, 0.f, 0.f};
  f32x4 acc[2][4];
#pragma unroll
  for (int mt = 0; mt < 2; ++mt)
#pragma unroll
    for (int nt = 0; nt < 4; ++nt) acc[mt][nt] = zf;

  for (int kk = 0; kk < CC; kk += 32) {
    __syncthreads();
    // stage W tile: 128 ch x 32 c (f32 -> bf16)
#pragma unroll
    for (int u = 0; u < 4; ++u) {
      int e = tid + (u << 8);
      int row = e >> 3, cq = (e & 7) * 4;
      float4 w4 = *(const float4*)&Wm[row * CC + kk + cq];
      unsigned* dst = (unsigned*)(Wt + row * 40 + cq);
      dst[0] = pk2(w4.x, w4.y);
      dst[1] = pk2(w4.z, w4.w);
    }
    // stage X tile transposed: 32 c x 64 px -> Xt[px][c]
#pragma unroll
    for (int u = 0; u < 2; ++u) {
      int e = tid + (u << 8);
      int c = e >> 4, p4 = (e & 15) * 4;
      float4 xv = *(const float4*)&X[((size_t)b * CC + kk + c) * HW + px0 + p4];
      Xt[(p4 + 0) * 40 + c] = f2b(xv.x);
      Xt[(p4 + 1) * 40 + c] = f2b(xv.y);
      Xt[(p4 + 2) * 40 + c] = f2b(xv.z);
      Xt[(p4 + 3) * 40 + c] = f2b(xv.w);
    }
    __syncthreads();
    bf16x8 af[2], bfr[4];
#pragma unroll
    for (int mt = 0; mt < 2; ++mt)
      af[mt] = *(const bf16x8*)(Wt + (wv * 32 + mt * 16 + t) * 40 + q * 8);
#pragma unroll
    for (int nt = 0; nt < 4; ++nt)
      bfr[nt] = *(const bf16x8*)(Xt + (nt * 16 + t) * 40 + q * 8);
#pragma unroll
    for (int mt = 0; mt < 2; ++mt)
#pragma unroll
      for (int nt = 0; nt < 4; ++nt)
        acc[mt][nt] = __builtin_amdgcn_mfma_f32_16x16x32_bf16(
            af[mt], bfr[nt], acc[mt][nt], 0, 0, 0);
  }
  __syncthreads();
  // D mapping (verified idiom): ch = wv*32 + mt*16 + q*4 + r, px = nt*16 + t
  if (which < 2) {
    // T[px][ch], stride 136 -> coalesced (B,HW,128) store
#pragma unroll
    for (int mt = 0; mt < 2; ++mt) {
      int chb = wv * 32 + mt * 16 + q * 4;
#pragma unroll
      for (int r = 0; r < 4; ++r) {
        float bv_ = bias[chb + r];
#pragma unroll
        for (int nt = 0; nt < 4; ++nt)
          T[(nt * 16 + t) * 136 + chb + r] = f2b(acc[mt][nt][r] + bv_);
      }
    }
    __syncthreads();
    short* out = (which == 0) ? qb : kb;
    int p = tid >> 2, cq = (tid & 3) * 32;
    short* gdst = out + ((size_t)b * HW + px0 + p) * DD + cq;
#pragma unroll
    for (int e2 = 0; e2 < 4; ++e2)
      *(uint4*)(gdst + e2 * 8) = *(const uint4*)(T + p * 136 + cq + e2 * 8);
  } else {
    // T[ch][px], stride 72 -> coalesced (B,128,HW) store
#pragma unroll
    for (int mt = 0; mt < 2; ++mt) {
      int chb = wv * 32 + mt * 16 + q * 4;
#pragma unroll
      for (int r = 0; r < 4; ++r) {
        float bv_ = bias[chb + r];
#pragma unroll
        for (int nt = 0; nt < 4; ++nt)
          T[(chb + r) * 72 + nt * 16 + t] = f2b(acc[mt][nt][r] + bv_);
      }
    }
    __syncthreads();
    int ch = tid >> 1, pq = (tid & 1) * 32;
    short* gdst = vb + ((size_t)b * DD + ch) * HW + px0 + pq;
#pragma unroll
    for (int e2 = 0; e2 < 4; ++e2)
      *(uint4*)(gdst + e2 * 8) = *(const uint4*)(T + ch * 72 + pq + e2 * 8);
  }
}

// ---------------- K2: pass1 MFMA partial sums: rl[j] += sum_{i in range} exp(s[i,j])
// i-range split x4 across blockIdx.y for occupancy; rl pre-zeroed.
__global__ __launch_bounds__(256) void k_lsum2(
    const short* __restrict__ qb, const short* __restrict__ kb,
    float* __restrict__ rl)
{
  __shared__ float lred[4][64];
  const int tid = threadIdx.x;
  const int w = tid >> 6;
  const int lane = tid & 63;
  const int t = lane & 15, q = lane >> 4;
  const int j0 = blockIdx.x * 64;
  const int ibeg = blockIdx.y * 1024;
  const int b = blockIdx.z;
  const short* qbb = qb + (size_t)b * HW * DD;
  const short* kbb = kb + (size_t)b * HW * DD;

  bf16x8 Bq[4][4];
#pragma unroll
  for (int nt = 0; nt < 4; ++nt)
#pragma unroll
    for (int kk = 0; kk < 4; ++kk)
      Bq[nt][kk] = *(const bf16x8*)(qbb + (size_t)(j0 + nt * 16 + t) * DD + kk * 32 + q * 8);

  float racc[4] = {0.f, 0.f, 0.f, 0.f};
  const f32x4 zf = {0.f, 0.f, 0.f, 0.f};

  for (int i = ibeg + w * 16; i < ibeg + 1024; i += 64) {
    bf16x8 Ak[4];
#pragma unroll
    for (int kk = 0; kk < 4; ++kk)
      Ak[kk] = *(const bf16x8*)(kbb + (size_t)(i + t) * DD + kk * 32 + q * 8);
#pragma unroll
    for (int nt = 0; nt < 4; ++nt) {
      f32x4 d = zf;
#pragma unroll
      for (int kk = 0; kk < 4; ++kk)
        d = __builtin_amdgcn_mfma_f32_16x16x32_bf16(Ak[kk], Bq[nt][kk], d, 0, 0, 0);
      racc[nt] += __expf(d[0]) + __expf(d[1]) + __expf(d[2]) + __expf(d[3]);
    }
  }
#pragma unroll
  for (int nt = 0; nt < 4; ++nt) {
    float r = racc[nt];
    r += __shfl_xor(r, 16);
    r += __shfl_xor(r, 32);
    if (q == 0) lred[w][nt * 16 + t] = r;
  }
  __syncthreads();
  if (tid < 64) {
    float sum = lred[0][tid] + lred[1][tid] + lred[2][tid] + lred[3][tid];
    atomicAdd(&rl[(size_t)b * HW + j0 + tid], sum);
  }
}

// ---------------- K2b: vs[c][j] = bf16( vb[c][j] / l_j )   (B,128,HW)
__global__ __launch_bounds__(256) void k_vs(
    const short* __restrict__ vb, const float* __restrict__ rl,
    short* __restrict__ vs)
{
  int id4 = (blockIdx.x * 256 + threadIdx.x) * 4;
  int j = id4 & (HW - 1);
  int b = id4 >> 19;
  uint2 pv = *(const uint2*)(vb + id4);
  float f0 = __uint_as_float(pv.x << 16);
  float f1 = __uint_as_float(pv.x & 0xffff0000u);
  float f2 = __uint_as_float(pv.y << 16);
  float f3 = __uint_as_float(pv.y & 0xffff0000u);
  const float* rlb = rl + (size_t)b * HW + j;
  unsigned u0 = pk2(f0 / rlb[0], f1 / rlb[1]);
  unsigned u1 = pk2(f2 / rlb[2], f3 / rlb[3]);
  *(uint2*)(vs + id4) = make_uint2(u0, u1);
}

// ---------------- K3: pass2, R0 structure (LDS-P, b128 PV reads) +
//  (a) T14 async-STAGE: tile t+1's global loads issued before compute of t,
//      ds_write at next iteration's top (latency hides under S/exp/PV).
//  (b) P stride 76: breaks q/q+2 row aliasing on P-writes.
__global__ __launch_bounds__(256, 2) void k_attn2(
    const short* __restrict__ qb, const short* __restrict__ kb,
    const short* __restrict__ vs, float* __restrict__ ao)
{
  __shared__ __align__(16) short Qs[64 * 136];   // [j][c], stride 136 shorts
  __shared__ __align__(16) short Vss[128 * 72];  // [c][j], stride 72 shorts
  __shared__ __align__(16) short P[4][16][76];   // per-wave P tile, stride 76
  const int tid = threadIdx.x;
  const int w = tid >> 6;
  const int lane = tid & 63;
  const int t = lane & 15, q = lane >> 4;
  const int b = blockIdx.z;
  const int i0 = blockIdx.x * 64 + w * 16;
  const int jbeg = blockIdx.y * 2048, jend = jbeg + 2048;
  const short* qbb = qb + (size_t)b * HW * DD;
  const short* kbb = kb + (size_t)b * HW * DD;
  const short* vsb = vs + (size_t)b * DD * HW;
  const f32x4 zf = {0.f, 0.f, 0.f, 0.f};

  bf16x8 Ak[4];
#pragma unroll
  for (int kk = 0; kk < 4; ++kk)
    Ak[kk] = *(const bf16x8*)(kbb + (size_t)(i0 + t) * DD + kk * 32 + q * 8);

  f32x4 acc[8];
#pragma unroll
  for (int nt = 0; nt < 8; ++nt) acc[nt] = zf;

  // T14 prologue: prefetch tile jbeg into registers
  bf16x8 rq[4], rv[4];
#pragma unroll
  for (int r = 0; r < 4; ++r) {
    int e = tid + (r << 8);
    rq[r] = *(const bf16x8*)(qbb + (size_t)(jbeg + (e >> 4)) * DD + (e & 15) * 8);
    rv[r] = *(const bf16x8*)(vsb + (size_t)(e >> 3) * HW + jbeg + (e & 7) * 8);
  }

  for (int j = jbeg; j < jend; j += 64) {
    __syncthreads();   // prior iteration's LDS reads complete
#pragma unroll
    for (int r = 0; r < 4; ++r) {
      int e = tid + (r << 8);
      *(bf16x8*)(Qs + (e >> 4) * 136 + (e & 15) * 8) = rq[r];
      *(bf16x8*)(Vss + (e >> 3) * 72 + (e & 7) * 8) = rv[r];
    }
    __syncthreads();
    // issue next tile's global loads early; consumed at next iter's ds_write
    if (j + 64 < jend) {
#pragma unroll
      for (int r = 0; r < 4; ++r) {
        int e = tid + (r << 8);
        rq[r] = *(const bf16x8*)(qbb + (size_t)(j + 64 + (e >> 4)) * DD + (e & 15) * 8);
        rv[r] = *(const bf16x8*)(vsb + (size_t)(e >> 3) * HW + j + 64 + (e & 7) * 8);
      }
    }
    // S: sv[nt][r] = S[i0 + q*4 + r][j + nt*16 + t]
    f32x4 sv[4];
#pragma unroll
    for (int nt = 0; nt < 4; ++nt) sv[nt] = zf;
#pragma unroll
    for (int nt = 0; nt < 4; ++nt)
#pragma unroll
      for (int kk = 0; kk < 4; ++kk) {
        bf16x8 bq = *(const bf16x8*)(Qs + (nt * 16 + t) * 136 + kk * 32 + q * 8);
        sv[nt] = __builtin_amdgcn_mfma_f32_16x16x32_bf16(Ak[kk], bq, sv[nt], 0, 0, 0);
      }
    // P round-trip (per-wave, stride 76)
#pragma unroll
    for (int nt = 0; nt < 4; ++nt)
#pragma unroll
      for (int r = 0; r < 4; ++r)
        P[w][q * 4 + r][nt * 16 + t] = f2b(__expf(sv[nt][r]));
    bf16x8 ap[2];
#pragma unroll
    for (int ks = 0; ks < 2; ++ks) {
      bf16x4 lo = *(const bf16x4*)&P[w][t][ks * 32 + q * 8];
      bf16x4 hi = *(const bf16x4*)&P[w][t][ks * 32 + q * 8 + 4];
      ap[ks] = __builtin_shufflevector(lo, hi, 0, 1, 2, 3, 4, 5, 6, 7);
    }
    // PV: b128 Vss reads (R0 pattern)
#pragma unroll
    for (int nt = 0; nt < 8; ++nt)
#pragma unroll
      for (int ks = 0; ks < 2; ++ks) {
        bf16x8 bv = *(const bf16x8*)(Vss + (nt * 16 + t) * 72 + ks * 32 + q * 8);
        acc[nt] = __builtin_amdgcn_mfma_f32_16x16x32_bf16(ap[ks], bv, acc[nt], 0, 0, 0);
      }
  }
  float* aob = ao + (size_t)b * DD * HW;
#pragma unroll
  for (int nt = 0; nt < 8; ++nt)
#pragma unroll
    for (int r = 0; r < 4; ++r)
      atomicAdd(&aob[(size_t)(nt * 16 + t) * HW + i0 + q * 4 + r], acc[nt][r]);
}

// ---------------- K4: y = tgt + gamma*(Wp@ao + bp) -> Xn interior, ch [0,256)
// Xn layout: (B, 66, 66, 768) NHWC bf16 with a zeroed guard ring.
__global__ __launch_bounds__(256) void k_proj(
    const float* __restrict__ ao, const float* __restrict__ tgt,
    const float* __restrict__ Wp, const float* __restrict__ bp,
    const float* __restrict__ gamma, short* __restrict__ Xn)
{
  __shared__ float Wt[32][132];
  __shared__ float Xs[32][68];
  __shared__ float T[64][133];
  const int tid = threadIdx.x;
  const int tx = tid & 15, ty = tid >> 4;
  const int p0 = blockIdx.x * 64;
  const int ro = blockIdx.y * 128;
  const int b = blockIdx.z;
  const float g0 = gamma[0];

  float acc[8][4];
#pragma unroll
  for (int i = 0; i < 8; ++i)
#pragma unroll
    for (int j = 0; j < 4; ++j) acc[i][j] = 0.f;

  for (int kk = 0; kk < DD; kk += 32) {
    __syncthreads();
#pragma unroll
    for (int u = 0; u < 4; ++u) {
      int e = tid + 256 * u;
      int c4 = (e & 7) * 4, r = e >> 3;
      float w[4]; ld4(w, &Wp[(ro + r) * DD + kk + c4]);
      Wt[c4 + 0][r] = w[0]; Wt[c4 + 1][r] = w[1];
      Wt[c4 + 2][r] = w[2]; Wt[c4 + 3][r] = w[3];
    }
#pragma unroll
    for (int u = 0; u < 2; ++u) {
      int e = tid + 256 * u;
      int p4 = (e & 15) * 4, c = e >> 4;
      *(float4*)&Xs[c][p4] = *(const float4*)&ao[(b * DD + kk + c) * HW + p0 + p4];
    }
    __syncthreads();
#pragma unroll 4
    for (int c = 0; c < 32; ++c) {
      float wa[8], xb[4];
      ld4(wa, &Wt[c][ty * 8]); ld4(wa + 4, &Wt[c][ty * 8 + 4]);
      ld4(xb, &Xs[c][tx * 4]);
#pragma unroll
      for (int rr = 0; rr < 8; ++rr)
#pragma unroll
        for (int pp = 0; pp < 4; ++pp) acc[rr][pp] += wa[rr] * xb[pp];
    }
  }
#pragma unroll
  for (int rr = 0; rr < 8; ++rr) {
    int r = ro + ty * 8 + rr;
    int idx = (b * CC + r) * HW + p0 + tx * 4;
    float4 t4 = *(const float4*)&tgt[idx];
    float bpv = bp[r];
    T[tx * 4 + 0][ty * 8 + rr] = t4.x + g0 * (acc[rr][0] + bpv);
    T[tx * 4 + 1][ty * 8 + rr] = t4.y + g0 * (acc[rr][1] + bpv);
    T[tx * 4 + 2][ty * 8 + rr] = t4.z + g0 * (acc[rr][2] + bpv);
    T[tx * 4 + 3][ty * 8 + rr] = t4.w + g0 * (acc[rr][3] + bpv);
  }
  __syncthreads();
  {
    int p = tid >> 2, cq = (tid & 3) * 32;
    int h = p0 >> 6;
    unsigned* dst = (unsigned*)(Xn + ((((size_t)b * 66 + h + 1) * 66) + 1 + p) * 768 + ro + cq);
#pragma unroll
    for (int e = 0; e < 16; ++e)
      dst[e] = pk2(T[p][cq + 2 * e], T[p][cq + 2 * e + 1]);
  }
}

// ---------------- K4b: upsample prev into Xn interior, channels [256,768)
__global__ __launch_bounds__(256) void k_pack(
    const float* __restrict__ prev, short* __restrict__ Xn)
{
  __shared__ float tile[64][65];
  const int tid = threadIdx.x;
  const int h = blockIdx.x;
  const int ci0 = blockIdx.y * 64;
  const int b = blockIdx.z;

  {
    int w = tid & 63, r = tid >> 6;
    for (int cs = r; cs < 64; cs += 4)
      tile[cs][w] = prev[((size_t)b * 512 + ci0 + cs) * 1024 + (h >> 1) * 32 + (w >> 1)];
  }
  __syncthreads();
  {
    int ci = tid & 63, wq = tid >> 6;
    for (int ws2 = wq; ws2 < 64; ws2 += 4)
      Xn[((((size_t)b * 66 + h + 1) * 66) + 1 + ws2) * 768 + 256 + ci0 + ci] = f2b(tile[ci][ws2]);
  }
}

// ---------------- K4c: weight repack Wc(256,768,3,3) f32 -> Wb(256,9,768) bf16
__global__ __launch_bounds__(256) void k_wb(
    const float* __restrict__ Wc, short* __restrict__ Wb)
{
  int i = blockIdx.x * 256 + threadIdx.x;
  int o = i / 6912;
  int rem = i - o * 6912;
  int khw = rem / 768;
  int ci = rem - khw * 768;
  Wb[i] = f2b(Wc[(size_t)o * 6912 + ci * 9 + khw]);
}

// ---------------- K5: 3x3 conv, R2 structure (64x2x4 grid, 2 blocks/CU,
// 2 barriers/stage) with staging switched to global_load_lds DMA:
// no VGPR round-trip, no ds_write instructions, no staging VALU.
// LDS tiles are LINEAR stride-64 (DMA requires lane-linear dest); the
// 128B-row read conflict is broken by a both-sides XOR involution:
//   LDS slot (row, g) <- global granule (g ^ (row&7));
//   read granule G at slot (G ^ (row&7)).
// Operand values are bit-identical to R2 -> epilogue mapping unchanged.
__global__ __launch_bounds__(256, 2) void k_conv_mfma(
    const short* __restrict__ Xn,   // (B,66,66,768) bf16, guard ring zero
    const short* __restrict__ Wb,   // (256,9,768) bf16
    const float* __restrict__ bcw,
    short* __restrict__ cb)         // (B,256,4096) bf16
{
  __shared__ __align__(16) short Wl[384 * 64];  // 48 KB, [kw*128+cout][64ci]
  __shared__ __align__(16) short Xl[66 * 64];   // 8.25 KB, [px][64ci]
  const int tid = threadIdx.x;
  const int wv = tid >> 6;
  const int lane = tid & 63;
  const int t = lane & 15, q = lane >> 4;
  const int h = blockIdx.x;
  const int m0blk = blockIdx.y * 128;
  const int b = blockIdx.z;

  const f32x4 zf = {0.f, 0.f, 0.f, 0.f};
  f32x4 acc[2][4];
#pragma unroll
  for (int mt = 0; mt < 2; ++mt)
#pragma unroll
    for (int nt = 0; nt < 4; ++nt) acc[mt][nt] = zf;

  for (int kh = 0; kh < 3; ++kh) {
    const short* wsrc = Wb + (size_t)m0blk * 6912 + (kh * 3) * 768;
    const short* xsrc = Xn + ((size_t)b * 66 + h + kh) * 66 * 768;
    for (int ci0 = 0; ci0 < 768; ci0 += 64) {
      // stage W: 384 rows x 8 granules(16B) = 3072; 12 DMA per thread
#pragma unroll
      for (int r = 0; r < 12; ++r) {
        int e = tid + (r << 8);
        int g = e & 7, row = e >> 3;
        int kw = row >> 7, cout = row & 127;
        int gs = g ^ (row & 7);
        gl16(wsrc + (size_t)cout * 6912 + kw * 768 + ci0 + gs * 8, Wl + e * 8);
      }
      // stage X: 66 rows x 8 granules = 528
#pragma unroll
      for (int r = 0; r < 3; ++r) {
        int e = tid + (r << 8);
        if (e < 528) {
          int g = e & 7, px = e >> 3;
          int gs = g ^ (px & 7);
          gl16(xsrc + (size_t)px * 768 + ci0 + gs * 8, Xl + e * 8);
        }
      }
      __syncthreads();
#pragma unroll
      for (int kw = 0; kw < 3; ++kw) {
        bf16x8 af[2][2], bfr[4][2];
#pragma unroll
        for (int kk = 0; kk < 2; ++kk) {
#pragma unroll
          for (int mt = 0; mt < 2; ++mt) {
            int row = kw * 128 + wv * 32 + mt * 16 + t;
            int g = (kk * 4 + q) ^ (row & 7);
            af[mt][kk] = *(const bf16x8*)(Wl + row * 64 + g * 8);
          }
#pragma unroll
          for (int nt = 0; nt < 4; ++nt) {
            int row = nt * 16 + t + kw;
            int g = (kk * 4 + q) ^ (row & 7);
            bfr[nt][kk] = *(const bf16x8*)(Xl + row * 64 + g * 8);
          }
        }
#pragma unroll
        for (int kk = 0; kk < 2; ++kk)
#pragma unroll
          for (int mt = 0; mt < 2; ++mt)
#pragma unroll
            for (int nt = 0; nt < 4; ++nt)
              acc[mt][nt] = __builtin_amdgcn_mfma_f32_16x16x32_bf16(
                  af[mt][kk], bfr[nt][kk], acc[mt][nt], 0, 0, 0);
      }
      __syncthreads();
    }
  }
  // D mapping: outch = m0blk + wv*32 + mt*16 + q*4 + r ; px = nt*16 + t
#pragma unroll
  for (int mt = 0; mt < 2; ++mt) {
    int om = m0blk + wv * 32 + mt * 16 + q * 4;
#pragma unroll
    for (int r = 0; r < 4; ++r) {
      float bias = bcw[om + r];
      short* orow = cb + ((size_t)b * CC + om + r) * HW + h * 64;
#pragma unroll
      for (int nt = 0; nt < 4; ++nt)
        orow[nt * 16 + t] = f2b(acc[mt][nt][r] + bias);
    }
  }
}

// ---------------- K6: InstanceNorm (biased var, eps=1e-5) + ReLU; bf16 in, f32 out
__global__ __launch_bounds__(256) void k_inorm(
    const short* __restrict__ cb, float* __restrict__ out)
{
  __shared__ float buf[4096];
  __shared__ float red[8];
  const int tid = threadIdx.x;
  const int ch = blockIdx.x;
  const short* srcp = cb + (size_t)ch * HW;

  float s = 0.f, sq = 0.f;
#pragma unroll
  for (int u = 0; u < 2; ++u) {
    int sidx = u * 2048 + tid * 8;
    uint4 pk = *(const uint4*)(srcp + sidx);
    float f[8];
    f[0] = __uint_as_float(pk.x << 16); f[1] = __uint_as_float(pk.x & 0xffff0000u);
    f[2] = __uint_as_float(pk.y << 16); f[3] = __uint_as_float(pk.y & 0xffff0000u);
    f[4] = __uint_as_float(pk.z << 16); f[5] = __uint_as_float(pk.z & 0xffff0000u);
    f[6] = __uint_as_float(pk.w << 16); f[7] = __uint_as_float(pk.w & 0xffff0000u);
#pragma unroll
    for (int e = 0; e < 8; ++e) {
      buf[sidx + e] = f[e];
      s += f[e];
      sq += f[e] * f[e];
    }
  }
#pragma unroll
  for (int m = 32; m >= 1; m >>= 1) {
    s  += __shfl_xor(s, m, 64);
    sq += __shfl_xor(sq, m, 64);
  }
  if ((tid & 63) == 0) { red[tid >> 6] = s; red[4 + (tid >> 6)] = sq; }
  __syncthreads();
  if (tid == 0) {
    float S = red[0] + red[1] + red[2] + red[3];
    float Q = red[4] + red[5] + red[6] + red[7];
    float mean = S * (1.f / HW);
    float var = Q * (1.f / HW) - mean * mean;
    red[0] = mean;
    red[1] = rsqrtf(var + 1e-5f);
  }
  __syncthreads();
  const float mean = red[0], rs = red[1];
#pragma unroll
  for (int u = 0; u < 4; ++u) {
    int idx = u * 1024 + tid * 4;
    float4 v = *(const float4*)&buf[idx];
    float4 o4 = make_float4(fmaxf((v.x - mean) * rs, 0.f),
                            fmaxf((v.y - mean) * rs, 0.f),
                            fmaxf((v.z - mean) * rs, 0.f),
                            fmaxf((v.w - mean) * rs, 0.f));
    *(float4*)&out[(size_t)ch * HW + idx] = o4;
  }
}

extern "C" void kernel_launch(void* const* d_in, const int* in_sizes, int n_in,
                              void* d_out, int out_size, void* d_ws, size_t ws_size,
                              hipStream_t stream) {
  const float* src  = (const float*)d_in[0];
  const float* tgt  = (const float*)d_in[1];
  const float* prev = (const float*)d_in[2];
  const float* Wq = (const float*)d_in[3];  const float* bq = (const float*)d_in[4];
  const float* Wk = (const float*)d_in[5];  const float* bk = (const float*)d_in[6];
  const float* Wv = (const float*)d_in[7];  const float* bv = (const float*)d_in[8];
  const float* Wp = (const float*)d_in[9];  const float* bp = (const float*)d_in[10];
  const float* gamma = (const float*)d_in[11];
  const float* Wc = (const float*)d_in[12]; const float* bcw = (const float*)d_in[13];

  float* ws = (float*)d_ws;
  // float-unit offsets; lifetimes:
  short* qb = (short*)ws;                 // [0, 1048576)        dead after k_attn2
  short* kb = (short*)(ws + 1048576);     // [1048576, 2097152)  dead after k_attn2
  short* vb = (short*)(ws + 2097152);     // [2097152, 3145728)  dead after k_vs
  float* rl = ws + 3145728;               // [3145728, 3162112)  dead after k_vs
  short* vs = (short*)(ws + 3162112);     // [3162112, 4210688)  dead after k_attn2
  short* Xn = (short*)ws;                 // [0, 6690816)  (B,66,66,768) over qb/kb/vb/rl/vs
  float* ao = ws + 6690816;               // [6690816, 8787968)  zeroed before attn2
  short* cb = (short*)(ws + 6690816);     // over ao (ao dead after k_proj)
  short* Wb = (short*)(ws + 8787968);     // [8787968, 9672704)
  // high-water: 9,672,704 floats = 38.7 MB

  k_qkv_mfma<<<dim3(64, 3, BB), 256, 0, stream>>>(src, tgt, Wq, bq, Wk, bk, Wv, bv, qb, kb, vb);
  hipMemsetAsync(rl, 0, (size_t)BB * HW * 4, stream);
  k_lsum2<<<dim3(64, 4, BB), 256, 0, stream>>>(qb, kb, rl);
  k_vs   <<<dim3(2048),      256, 0, stream>>>(vb, rl, vs);
  hipMemsetAsync(ao, 0, (size_t)2097152 * 4, stream);
  k_attn2<<<dim3(64, 2, BB), 256, 0, stream>>>(qb, kb, vs, ao);
  // Xn overlaps qb/kb/vb/rl/vs -> zero only after k_attn2 (also zeroes guard ring)
  hipMemsetAsync(Xn, 0, (size_t)BB * 66 * 66 * 768 * 2, stream);
  k_proj <<<dim3(64, 2, BB), 256, 0, stream>>>(ao, tgt, Wp, bp, gamma, Xn);
  k_pack <<<dim3(64, 8, BB), 256, 0, stream>>>(prev, Xn);
  k_wb   <<<dim3(6912),      256, 0, stream>>>(Wc, Wb);
  k_conv_mfma<<<dim3(64, 2, BB), 256, 0, stream>>>(Xn, Wb, bcw, cb);
  k_inorm<<<dim3(1024),      256, 0, stream>>>(cb, (float*)d_out);
}

// Round 6
// 376.391 us; speedup vs baseline: 1.5639x; 1.0154x over previous
//
#include <hip/hip_runtime.h>
#include <hip/hip_bf16.h>

#define BB 4
#define CC 256
#define HW 4096
#define DD 128

typedef __attribute__((ext_vector_type(8))) short bf16x8;
typedef __attribute__((ext_vector_type(4))) short bf16x4;
typedef __attribute__((ext_vector_type(4))) float f32x4;
typedef __attribute__((ext_vector_type(4))) unsigned uint4v;

static __device__ __forceinline__ void ld4(float* dst, const float* src) {
  float4 t = *(const float4*)src;
  dst[0] = t.x; dst[1] = t.y; dst[2] = t.z; dst[3] = t.w;
}

// float -> bf16 (RNE) raw bits
static __device__ __forceinline__ short f2b(float f) {
  unsigned u = __float_as_uint(f);
  u += 0x7fffu + ((u >> 16) & 1u);
  return (short)(u >> 16);
}
static __device__ __forceinline__ unsigned pk2(float lo, float hi) {
  return (unsigned)(unsigned short)f2b(lo) | ((unsigned)(unsigned short)f2b(hi) << 16);
}

// async global->LDS DMA, 16B per lane; LDS dest must be linear in lane order
static __device__ __forceinline__ void gl16(const short* g, short* l) {
  __builtin_amdgcn_global_load_lds(
      (const __attribute__((address_space(1))) unsigned*)g,
      (__attribute__((address_space(3))) unsigned*)l, 16, 0, 0);
}

// ---------------- K1: q/k/v 1x1 conv as LDS-staged bf16 MFMA.
// Per (pxtile, which, b): GEMM W(128x256) @ X(256x64px).
// Outputs: q,k -> (B,HW,128) bf16 (pre-transposed for attention);
//          v   -> (B,128,HW) bf16.
__global__ __launch_bounds__(256) void k_qkv_mfma(
    const float* __restrict__ src, const float* __restrict__ tgt,
    const float* __restrict__ Wq, const float* __restrict__ bq,
    const float* __restrict__ Wk, const float* __restrict__ bk,
    const float* __restrict__ Wv, const float* __restrict__ bv,
    short* __restrict__ qb, short* __restrict__ kb, short* __restrict__ vb)
{
  __shared__ __align__(16) short Wt[128 * 40];  // [ch][c], stride 40 (2-way free)
  __shared__ __align__(16) short Xt[64 * 40];   // [px][c]
  __shared__ __align__(16) short T[9216];       // epilogue tile
  const int tid = threadIdx.x;
  const int wv = tid >> 6;
  const int lane = tid & 63;
  const int t = lane & 15, q = lane >> 4;
  const int px0 = blockIdx.x * 64;
  const int which = blockIdx.y;
  const int b = blockIdx.z;
  const float* X    = (which == 0) ? src : tgt;
  const float* Wm   = (which == 0) ? Wq : (which == 1) ? Wk : Wv;
  const float* bias = (which == 0) ? bq : (which == 1) ? bk : bv;

  const f32x4 zf = {0.f, 0.f, 0.f, 0.f};
  f32x4 acc[2][4];
#pragma unroll
  for (int mt = 0; mt < 2; ++mt)
#pragma unroll
    for (int nt = 0; nt < 4; ++nt) acc[mt][nt] = zf;

  for (int kk = 0; kk < CC; kk += 32) {
    __syncthreads();
    // stage W tile: 128 ch x 32 c (f32 -> bf16)
#pragma unroll
    for (int u = 0; u < 4; ++u) {
      int e = tid + (u << 8);
      int row = e >> 3, cq = (e & 7) * 4;
      float4 w4 = *(const float4*)&Wm[row * CC + kk + cq];
      unsigned* dst = (unsigned*)(Wt + row * 40 + cq);
      dst[0] = pk2(w4.x, w4.y);
      dst[1] = pk2(w4.z, w4.w);
    }
    // stage X tile transposed: 32 c x 64 px -> Xt[px][c]
#pragma unroll
    for (int u = 0; u < 2; ++u) {
      int e = tid + (u << 8);
      int c = e >> 4, p4 = (e & 15) * 4;
      float4 xv = *(const float4*)&X[((size_t)b * CC + kk + c) * HW + px0 + p4];
      Xt[(p4 + 0) * 40 + c] = f2b(xv.x);
      Xt[(p4 + 1) * 40 + c] = f2b(xv.y);
      Xt[(p4 + 2) * 40 + c] = f2b(xv.z);
      Xt[(p4 + 3) * 40 + c] = f2b(xv.w);
    }
    __syncthreads();
    bf16x8 af[2], bfr[4];
#pragma unroll
    for (int mt = 0; mt < 2; ++mt)
      af[mt] = *(const bf16x8*)(Wt + (wv * 32 + mt * 16 + t) * 40 + q * 8);
#pragma unroll
    for (int nt = 0; nt < 4; ++nt)
      bfr[nt] = *(const bf16x8*)(Xt + (nt * 16 + t) * 40 + q * 8);
#pragma unroll
    for (int mt = 0; mt < 2; ++mt)
#pragma unroll
      for (int nt = 0; nt < 4; ++nt)
        acc[mt][nt] = __builtin_amdgcn_mfma_f32_16x16x32_bf16(
            af[mt], bfr[nt], acc[mt][nt], 0, 0, 0);
  }
  __syncthreads();
  // D mapping (verified idiom): ch = wv*32 + mt*16 + q*4 + r, px = nt*16 + t
  if (which < 2) {
    // T[px][ch], stride 136 -> coalesced (B,HW,128) store
#pragma unroll
    for (int mt = 0; mt < 2; ++mt) {
      int chb = wv * 32 + mt * 16 + q * 4;
#pragma unroll
      for (int r = 0; r < 4; ++r) {
        float bv_ = bias[chb + r];
#pragma unroll
        for (int nt = 0; nt < 4; ++nt)
          T[(nt * 16 + t) * 136 + chb + r] = f2b(acc[mt][nt][r] + bv_);
      }
    }
    __syncthreads();
    short* out = (which == 0) ? qb : kb;
    int p = tid >> 2, cq = (tid & 3) * 32;
    short* gdst = out + ((size_t)b * HW + px0 + p) * DD + cq;
#pragma unroll
    for (int e2 = 0; e2 < 4; ++e2)
      *(uint4*)(gdst + e2 * 8) = *(const uint4*)(T + p * 136 + cq + e2 * 8);
  } else {
    // T[ch][px], stride 72 -> coalesced (B,128,HW) store
#pragma unroll
    for (int mt = 0; mt < 2; ++mt) {
      int chb = wv * 32 + mt * 16 + q * 4;
#pragma unroll
      for (int r = 0; r < 4; ++r) {
        float bv_ = bias[chb + r];
#pragma unroll
        for (int nt = 0; nt < 4; ++nt)
          T[(chb + r) * 72 + nt * 16 + t] = f2b(acc[mt][nt][r] + bv_);
      }
    }
    __syncthreads();
    int ch = tid >> 1, pq = (tid & 1) * 32;
    short* gdst = vb + ((size_t)b * DD + ch) * HW + px0 + pq;
#pragma unroll
    for (int e2 = 0; e2 < 4; ++e2)
      *(uint4*)(gdst + e2 * 8) = *(const uint4*)(T + ch * 72 + pq + e2 * 8);
  }
}

// ---------------- K2: pass1 MFMA partial sums: rl[j] += sum_{i in range} exp(s[i,j])
// i-range split x4 across blockIdx.y for occupancy; rl pre-zeroed.
__global__ __launch_bounds__(256) void k_lsum2(
    const short* __restrict__ qb, const short* __restrict__ kb,
    float* __restrict__ rl)
{
  __shared__ float lred[4][64];
  const int tid = threadIdx.x;
  const int w = tid >> 6;
  const int lane = tid & 63;
  const int t = lane & 15, q = lane >> 4;
  const int j0 = blockIdx.x * 64;
  const int ibeg = blockIdx.y * 1024;
  const int b = blockIdx.z;
  const short* qbb = qb + (size_t)b * HW * DD;
  const short* kbb = kb + (size_t)b * HW * DD;

  bf16x8 Bq[4][4];
#pragma unroll
  for (int nt = 0; nt < 4; ++nt)
#pragma unroll
    for (int kk = 0; kk < 4; ++kk)
      Bq[nt][kk] = *(const bf16x8*)(qbb + (size_t)(j0 + nt * 16 + t) * DD + kk * 32 + q * 8);

  float racc[4] = {0.f, 0.f, 0.f, 0.f};
  const f32x4 zf = {0.f, 0.f, 0.f, 0.f};

  for (int i = ibeg + w * 16; i < ibeg + 1024; i += 64) {
    bf16x8 Ak[4];
#pragma unroll
    for (int kk = 0; kk < 4; ++kk)
      Ak[kk] = *(const bf16x8*)(kbb + (size_t)(i + t) * DD + kk * 32 + q * 8);
#pragma unroll
    for (int nt = 0; nt < 4; ++nt) {
      f32x4 d = zf;
#pragma unroll
      for (int kk = 0; kk < 4; ++kk)
        d = __builtin_amdgcn_mfma_f32_16x16x32_bf16(Ak[kk], Bq[nt][kk], d, 0, 0, 0);
      racc[nt] += __expf(d[0]) + __expf(d[1]) + __expf(d[2]) + __expf(d[3]);
    }
  }
#pragma unroll
  for (int nt = 0; nt < 4; ++nt) {
    float r = racc[nt];
    r += __shfl_xor(r, 16);
    r += __shfl_xor(r, 32);
    if (q == 0) lred[w][nt * 16 + t] = r;
  }
  __syncthreads();
  if (tid < 64) {
    float sum = lred[0][tid] + lred[1][tid] + lred[2][tid] + lred[3][tid];
    atomicAdd(&rl[(size_t)b * HW + j0 + tid], sum);
  }
}

// ---------------- K2b: vs[c][j] = bf16( vb[c][j] / l_j )   (B,128,HW)
__global__ __launch_bounds__(256) void k_vs(
    const short* __restrict__ vb, const float* __restrict__ rl,
    short* __restrict__ vs)
{
  int id4 = (blockIdx.x * 256 + threadIdx.x) * 4;
  int j = id4 & (HW - 1);
  int b = id4 >> 19;
  uint2 pv = *(const uint2*)(vb + id4);
  float f0 = __uint_as_float(pv.x << 16);
  float f1 = __uint_as_float(pv.x & 0xffff0000u);
  float f2 = __uint_as_float(pv.y << 16);
  float f3 = __uint_as_float(pv.y & 0xffff0000u);
  const float* rlb = rl + (size_t)b * HW + j;
  unsigned u0 = pk2(f0 / rlb[0], f1 / rlb[1]);
  unsigned u1 = pk2(f2 / rlb[2], f3 / rlb[3]);
  *(uint2*)(vs + id4) = make_uint2(u0, u1);
}

// ---------------- K3: pass2, register-P version.
// S computed TRANSPOSED (mfma(Q,K)) so lane (t,q) holds
//   sv[nt][r] = S[i0+t][j + nt*16 + q*4 + r]  -- full P-row slice in regs.
// PV K-axis permutation j(k) = ks*32 + ((k&7)>>2)*16 + (k>>3)*4 + (k&3)
// is applied AT V-STAGING TIME (inverse perm maps each thread's 8
// contiguous j's to two contiguous 4-short chunks at kap, kap+8) so:
//   - A-fragment = 8 pk2 packs, zero cross-lane, zero LDS;
//   - PV B-reads stay linear ds_read_b128;
//   - global vs loads stay coalesced.
// P LDS buffer deleted (-20 LDS instrs/wave-iter). T14 prefetch kept.
__global__ __launch_bounds__(256, 2) void k_attn2(
    const short* __restrict__ qb, const short* __restrict__ kb,
    const short* __restrict__ vs, float* __restrict__ ao)
{
  __shared__ __align__(16) short Qs[64 * 136];   // [j][c], stride 136 shorts
  __shared__ __align__(16) short Vp[128 * 72];   // [c][kappa] permuted, stride 72
  const int tid = threadIdx.x;
  const int w = tid >> 6;
  const int lane = tid & 63;
  const int t = lane & 15, q = lane >> 4;
  const int b = blockIdx.z;
  const int i0 = blockIdx.x * 64 + w * 16;
  const int jbeg = blockIdx.y * 2048, jend = jbeg + 2048;
  const short* qbb = qb + (size_t)b * HW * DD;
  const short* kbb = kb + (size_t)b * HW * DD;
  const short* vsb = vs + (size_t)b * DD * HW;
  const f32x4 zf = {0.f, 0.f, 0.f, 0.f};

  bf16x8 Ak[4];
#pragma unroll
  for (int kk = 0; kk < 4; ++kk)
    Ak[kk] = *(const bf16x8*)(kbb + (size_t)(i0 + t) * DD + kk * 32 + q * 8);

  f32x4 acc[8];
#pragma unroll
  for (int nt = 0; nt < 8; ++nt) acc[nt] = zf;

  // T14 prologue: prefetch tile jbeg into registers
  bf16x8 rq[4], rv[4];
#pragma unroll
  for (int r = 0; r < 4; ++r) {
    int e = tid + (r << 8);
    rq[r] = *(const bf16x8*)(qbb + (size_t)(jbeg + (e >> 4)) * DD + (e & 15) * 8);
    rv[r] = *(const bf16x8*)(vsb + (size_t)(e >> 3) * HW + jbeg + (e & 7) * 8);
  }

  for (int j = jbeg; j < jend; j += 64) {
    __syncthreads();   // prior iteration's LDS reads complete
#pragma unroll
    for (int r = 0; r < 4; ++r) {
      int e = tid + (r << 8);
      *(bf16x8*)(Qs + (e >> 4) * 136 + (e & 15) * 8) = rq[r];
    }
    // permuted V staging: thread's 8 contiguous j's (u8*8..u8*8+7) land at
    // kappa = (u8>>2)*32 + (u8&1)*16 + ((u8>>1)&1)*4  (lo 4)  and kappa+8 (hi 4)
#pragma unroll
    for (int r = 0; r < 4; ++r) {
      int e = tid + (r << 8);
      int c = e >> 3, u8 = e & 7;
      int kap = (u8 >> 2) * 32 + (u8 & 1) * 16 + ((u8 >> 1) & 1) * 4;
      bf16x4 lo = __builtin_shufflevector(rv[r], rv[r], 0, 1, 2, 3);
      bf16x4 hi = __builtin_shufflevector(rv[r], rv[r], 4, 5, 6, 7);
      *(bf16x4*)(Vp + c * 72 + kap) = lo;
      *(bf16x4*)(Vp + c * 72 + kap + 8) = hi;
    }
    __syncthreads();
    // issue next tile's global loads early; consumed at next iter's ds_write
    if (j + 64 < jend) {
#pragma unroll
      for (int r = 0; r < 4; ++r) {
        int e = tid + (r << 8);
        rq[r] = *(const bf16x8*)(qbb + (size_t)(j + 64 + (e >> 4)) * DD + (e & 15) * 8);
        rv[r] = *(const bf16x8*)(vsb + (size_t)(e >> 3) * HW + j + 64 + (e & 7) * 8);
      }
    }
    // S^T MFMA: sv[nt][r] = S[i0+t][j + nt*16 + q*4 + r]
    f32x4 sv[4];
#pragma unroll
    for (int nt = 0; nt < 4; ++nt) sv[nt] = zf;
#pragma unroll
    for (int nt = 0; nt < 4; ++nt)
#pragma unroll
      for (int kk = 0; kk < 4; ++kk) {
        bf16x8 bq = *(const bf16x8*)(Qs + (nt * 16 + t) * 136 + kk * 32 + q * 8);
        sv[nt] = __builtin_amdgcn_mfma_f32_16x16x32_bf16(bq, Ak[kk], sv[nt], 0, 0, 0);
      }
    // exp in-register + pack PV A-fragments (no LDS, no cross-lane)
    bf16x8 ap[2];
#pragma unroll
    for (int ks = 0; ks < 2; ++ks) {
      unsigned w0 = pk2(__expf(sv[2 * ks][0]), __expf(sv[2 * ks][1]));
      unsigned w1 = pk2(__expf(sv[2 * ks][2]), __expf(sv[2 * ks][3]));
      unsigned w2 = pk2(__expf(sv[2 * ks + 1][0]), __expf(sv[2 * ks + 1][1]));
      unsigned w3 = pk2(__expf(sv[2 * ks + 1][2]), __expf(sv[2 * ks + 1][3]));
      uint4v pw = {w0, w1, w2, w3};
      ap[ks] = __builtin_bit_cast(bf16x8, pw);
    }
    // PV: linear b128 reads from permuted Vp
#pragma unroll
    for (int nt = 0; nt < 8; ++nt)
#pragma unroll
      for (int ks = 0; ks < 2; ++ks) {
        bf16x8 bv = *(const bf16x8*)(Vp + (nt * 16 + t) * 72 + ks * 32 + q * 8);
        acc[nt] = __builtin_amdgcn_mfma_f32_16x16x32_bf16(ap[ks], bv, acc[nt], 0, 0, 0);
      }
  }
  float* aob = ao + (size_t)b * DD * HW;
#pragma unroll
  for (int nt = 0; nt < 8; ++nt)
#pragma unroll
    for (int r = 0; r < 4; ++r)
      atomicAdd(&aob[(size_t)(nt * 16 + t) * HW + i0 + q * 4 + r], acc[nt][r]);
}

// ---------------- K4: y = tgt + gamma*(Wp@ao + bp) -> Xn interior, ch [0,256)
// Xn layout: (B, 66, 66, 768) NHWC bf16 with a zeroed guard ring.
__global__ __launch_bounds__(256) void k_proj(
    const float* __restrict__ ao, const float* __restrict__ tgt,
    const float* __restrict__ Wp, const float* __restrict__ bp,
    const float* __restrict__ gamma, short* __restrict__ Xn)
{
  __shared__ float Wt[32][132];
  __shared__ float Xs[32][68];
  __shared__ float T[64][133];
  const int tid = threadIdx.x;
  const int tx = tid & 15, ty = tid >> 4;
  const int p0 = blockIdx.x * 64;
  const int ro = blockIdx.y * 128;
  const int b = blockIdx.z;
  const float g0 = gamma[0];

  float acc[8][4];
#pragma unroll
  for (int i = 0; i < 8; ++i)
#pragma unroll
    for (int j = 0; j < 4; ++j) acc[i][j] = 0.f;

  for (int kk = 0; kk < DD; kk += 32) {
    __syncthreads();
#pragma unroll
    for (int u = 0; u < 4; ++u) {
      int e = tid + 256 * u;
      int c4 = (e & 7) * 4, r = e >> 3;
      float w[4]; ld4(w, &Wp[(ro + r) * DD + kk + c4]);
      Wt[c4 + 0][r] = w[0]; Wt[c4 + 1][r] = w[1];
      Wt[c4 + 2][r] = w[2]; Wt[c4 + 3][r] = w[3];
    }
#pragma unroll
    for (int u = 0; u < 2; ++u) {
      int e = tid + 256 * u;
      int p4 = (e & 15) * 4, c = e >> 4;
      *(float4*)&Xs[c][p4] = *(const float4*)&ao[(b * DD + kk + c) * HW + p0 + p4];
    }
    __syncthreads();
#pragma unroll 4
    for (int c = 0; c < 32; ++c) {
      float wa[8], xb[4];
      ld4(wa, &Wt[c][ty * 8]); ld4(wa + 4, &Wt[c][ty * 8 + 4]);
      ld4(xb, &Xs[c][tx * 4]);
#pragma unroll
      for (int rr = 0; rr < 8; ++rr)
#pragma unroll
        for (int pp = 0; pp < 4; ++pp) acc[rr][pp] += wa[rr] * xb[pp];
    }
  }
#pragma unroll
  for (int rr = 0; rr < 8; ++rr) {
    int r = ro + ty * 8 + rr;
    int idx = (b * CC + r) * HW + p0 + tx * 4;
    float4 t4 = *(const float4*)&tgt[idx];
    float bpv = bp[r];
    T[tx * 4 + 0][ty * 8 + rr] = t4.x + g0 * (acc[rr][0] + bpv);
    T[tx * 4 + 1][ty * 8 + rr] = t4.y + g0 * (acc[rr][1] + bpv);
    T[tx * 4 + 2][ty * 8 + rr] = t4.z + g0 * (acc[rr][2] + bpv);
    T[tx * 4 + 3][ty * 8 + rr] = t4.w + g0 * (acc[rr][3] + bpv);
  }
  __syncthreads();
  {
    int p = tid >> 2, cq = (tid & 3) * 32;
    int h = p0 >> 6;
    unsigned* dst = (unsigned*)(Xn + ((((size_t)b * 66 + h + 1) * 66) + 1 + p) * 768 + ro + cq);
#pragma unroll
    for (int e = 0; e < 16; ++e)
      dst[e] = pk2(T[p][cq + 2 * e], T[p][cq + 2 * e + 1]);
  }
}

// ---------------- K4b: upsample prev into Xn interior, channels [256,768)
__global__ __launch_bounds__(256) void k_pack(
    const float* __restrict__ prev, short* __restrict__ Xn)
{
  __shared__ float tile[64][65];
  const int tid = threadIdx.x;
  const int h = blockIdx.x;
  const int ci0 = blockIdx.y * 64;
  const int b = blockIdx.z;

  {
    int w = tid & 63, r = tid >> 6;
    for (int cs = r; cs < 64; cs += 4)
      tile[cs][w] = prev[((size_t)b * 512 + ci0 + cs) * 1024 + (h >> 1) * 32 + (w >> 1)];
  }
  __syncthreads();
  {
    int ci = tid & 63, wq = tid >> 6;
    for (int ws2 = wq; ws2 < 64; ws2 += 4)
      Xn[((((size_t)b * 66 + h + 1) * 66) + 1 + ws2) * 768 + 256 + ci0 + ci] = f2b(tile[ci][ws2]);
  }
}

// ---------------- K4c: weight repack Wc(256,768,3,3) f32 -> Wb(256,9,768) bf16
__global__ __launch_bounds__(256) void k_wb(
    const float* __restrict__ Wc, short* __restrict__ Wb)
{
  int i = blockIdx.x * 256 + threadIdx.x;
  int o = i / 6912;
  int rem = i - o * 6912;
  int khw = rem / 768;
  int ci = rem - khw * 768;
  Wb[i] = f2b(Wc[(size_t)o * 6912 + ci * 9 + khw]);
}

// ---------------- K5: 3x3 conv, R2 structure (64x2x4 grid, 2 blocks/CU,
// 2 barriers/stage) with staging switched to global_load_lds DMA:
// no VGPR round-trip, no ds_write instructions, no staging VALU.
// LDS tiles are LINEAR stride-64 (DMA requires lane-linear dest); the
// 128B-row read conflict is broken by a both-sides XOR involution:
//   LDS slot (row, g) <- global granule (g ^ (row&7));
//   read granule G at slot (G ^ (row&7)).
// Operand values are bit-identical to R2 -> epilogue mapping unchanged.
__global__ __launch_bounds__(256, 2) void k_conv_mfma(
    const short* __restrict__ Xn,   // (B,66,66,768) bf16, guard ring zero
    const short* __restrict__ Wb,   // (256,9,768) bf16
    const float* __restrict__ bcw,
    short* __restrict__ cb)         // (B,256,4096) bf16
{
  __shared__ __align__(16) short Wl[384 * 64];  // 48 KB, [kw*128+cout][64ci]
  __shared__ __align__(16) short Xl[66 * 64];   // 8.25 KB, [px][64ci]
  const int tid = threadIdx.x;
  const int wv = tid >> 6;
  const int lane = tid & 63;
  const int t = lane & 15, q = lane >> 4;
  const int h = blockIdx.x;
  const int m0blk = blockIdx.y * 128;
  const int b = blockIdx.z;

  const f32x4 zf = {0.f, 0.f, 0.f, 0.f};
  f32x4 acc[2][4];
#pragma unroll
  for (int mt = 0; mt < 2; ++mt)
#pragma unroll
    for (int nt = 0; nt < 4; ++nt) acc[mt][nt] = zf;

  for (int kh = 0; kh < 3; ++kh) {
    const short* wsrc = Wb + (size_t)m0blk * 6912 + (kh * 3) * 768;
    const short* xsrc = Xn + ((size_t)b * 66 + h + kh) * 66 * 768;
    for (int ci0 = 0; ci0 < 768; ci0 += 64) {
      // stage W: 384 rows x 8 granules(16B) = 3072; 12 DMA per thread
#pragma unroll
      for (int r = 0; r < 12; ++r) {
        int e = tid + (r << 8);
        int g = e & 7, row = e >> 3;
        int kw = row >> 7, cout = row & 127;
        int gs = g ^ (row & 7);
        gl16(wsrc + (size_t)cout * 6912 + kw * 768 + ci0 + gs * 8, Wl + e * 8);
      }
      // stage X: 66 rows x 8 granules = 528
#pragma unroll
      for (int r = 0; r < 3; ++r) {
        int e = tid + (r << 8);
        if (e < 528) {
          int g = e & 7, px = e >> 3;
          int gs = g ^ (px & 7);
          gl16(xsrc + (size_t)px * 768 + ci0 + gs * 8, Xl + e * 8);
        }
      }
      __syncthreads();
#pragma unroll
      for (int kw = 0; kw < 3; ++kw) {
        bf16x8 af[2][2], bfr[4][2];
#pragma unroll
        for (int kk = 0; kk < 2; ++kk) {
#pragma unroll
          for (int mt = 0; mt < 2; ++mt) {
            int row = kw * 128 + wv * 32 + mt * 16 + t;
            int g = (kk * 4 + q) ^ (row & 7);
            af[mt][kk] = *(const bf16x8*)(Wl + row * 64 + g * 8);
          }
#pragma unroll
          for (int nt = 0; nt < 4; ++nt) {
            int row = nt * 16 + t + kw;
            int g = (kk * 4 + q) ^ (row & 7);
            bfr[nt][kk] = *(const bf16x8*)(Xl + row * 64 + g * 8);
          }
        }
#pragma unroll
        for (int kk = 0; kk < 2; ++kk)
#pragma unroll
          for (int mt = 0; mt < 2; ++mt)
#pragma unroll
            for (int nt = 0; nt < 4; ++nt)
              acc[mt][nt] = __builtin_amdgcn_mfma_f32_16x16x32_bf16(
                  af[mt][kk], bfr[nt][kk], acc[mt][nt], 0, 0, 0);
      }
      __syncthreads();
    }
  }
  // D mapping: outch = m0blk + wv*32 + mt*16 + q*4 + r ; px = nt*16 + t
#pragma unroll
  for (int mt = 0; mt < 2; ++mt) {
    int om = m0blk + wv * 32 + mt * 16 + q * 4;
#pragma unroll
    for (int r = 0; r < 4; ++r) {
      float bias = bcw[om + r];
      short* orow = cb + ((size_t)b * CC + om + r) * HW + h * 64;
#pragma unroll
      for (int nt = 0; nt < 4; ++nt)
        orow[nt * 16 + t] = f2b(acc[mt][nt][r] + bias);
    }
  }
}

// ---------------- K6: InstanceNorm (biased var, eps=1e-5) + ReLU; bf16 in, f32 out
__global__ __launch_bounds__(256) void k_inorm(
    const short* __restrict__ cb, float* __restrict__ out)
{
  __shared__ float buf[4096];
  __shared__ float red[8];
  const int tid = threadIdx.x;
  const int ch = blockIdx.x;
  const short* srcp = cb + (size_t)ch * HW;

  float s = 0.f, sq = 0.f;
#pragma unroll
  for (int u = 0; u < 2; ++u) {
    int sidx = u * 2048 + tid * 8;
    uint4 pk = *(const uint4*)(srcp + sidx);
    float f[8];
    f[0] = __uint_as_float(pk.x << 16); f[1] = __uint_as_float(pk.x & 0xffff0000u);
    f[2] = __uint_as_float(pk.y << 16); f[3] = __uint_as_float(pk.y & 0xffff0000u);
    f[4] = __uint_as_float(pk.z << 16); f[5] = __uint_as_float(pk.z & 0xffff0000u);
    f[6] = __uint_as_float(pk.w << 16); f[7] = __uint_as_float(pk.w & 0xffff0000u);
#pragma unroll
    for (int e = 0; e < 8; ++e) {
      buf[sidx + e] = f[e];
      s += f[e];
      sq += f[e] * f[e];
    }
  }
#pragma unroll
  for (int m = 32; m >= 1; m >>= 1) {
    s  += __shfl_xor(s, m, 64);
    sq += __shfl_xor(sq, m, 64);
  }
  if ((tid & 63) == 0) { red[tid >> 6] = s; red[4 + (tid >> 6)] = sq; }
  __syncthreads();
  if (tid == 0) {
    float S = red[0] + red[1] + red[2] + red[3];
    float Q = red[4] + red[5] + red[6] + red[7];
    float mean = S * (1.f / HW);
    float var = Q * (1.f / HW) - mean * mean;
    red[0] = mean;
    red[1] = rsqrtf(var + 1e-5f);
  }
  __syncthreads();
  const float mean = red[0], rs = red[1];
#pragma unroll
  for (int u = 0; u < 4; ++u) {
    int idx = u * 1024 + tid * 4;
    float4 v = *(const float4*)&buf[idx];
    float4 o4 = make_float4(fmaxf((v.x - mean) * rs, 0.f),
                            fmaxf((v.y - mean) * rs, 0.f),
                            fmaxf((v.z - mean) * rs, 0.f),
                            fmaxf((v.w - mean) * rs, 0.f));
    *(float4*)&out[(size_t)ch * HW + idx] = o4;
  }
}

extern "C" void kernel_launch(void* const* d_in, const int* in_sizes, int n_in,
                              void* d_out, int out_size, void* d_ws, size_t ws_size,
                              hipStream_t stream) {
  const float* src  = (const float*)d_in[0];
  const float* tgt  = (const float*)d_in[1];
  const float* prev = (const float*)d_in[2];
  const float* Wq = (const float*)d_in[3];  const float* bq = (const float*)d_in[4];
  const float* Wk = (const float*)d_in[5];  const float* bk = (const float*)d_in[6];
  const float* Wv = (const float*)d_in[7];  const float* bv = (const float*)d_in[8];
  const float* Wp = (const float*)d_in[9];  const float* bp = (const float*)d_in[10];
  const float* gamma = (const float*)d_in[11];
  const float* Wc = (const float*)d_in[12]; const float* bcw = (const float*)d_in[13];

  float* ws = (float*)d_ws;
  // float-unit offsets; lifetimes:
  short* qb = (short*)ws;                 // [0, 1048576)        dead after k_attn2
  short* kb = (short*)(ws + 1048576);     // [1048576, 2097152)  dead after k_attn2
  short* vb = (short*)(ws + 2097152);     // [2097152, 3145728)  dead after k_vs
  float* rl = ws + 3145728;               // [3145728, 3162112)  dead after k_vs
  short* vs = (short*)(ws + 3162112);     // [3162112, 4210688)  dead after k_attn2
  short* Xn = (short*)ws;                 // [0, 6690816)  (B,66,66,768) over qb/kb/vb/rl/vs
  float* ao = ws + 6690816;               // [6690816, 8787968)  zeroed before attn2
  short* cb = (short*)(ws + 6690816);     // over ao (ao dead after k_proj)
  short* Wb = (short*)(ws + 8787968);     // [8787968, 9672704)
  // high-water: 9,672,704 floats = 38.7 MB

  k_qkv_mfma<<<dim3(64, 3, BB), 256, 0, stream>>>(src, tgt, Wq, bq, Wk, bk, Wv, bv, qb, kb, vb);
  hipMemsetAsync(rl, 0, (size_t)BB * HW * 4, stream);
  k_lsum2<<<dim3(64, 4, BB), 256, 0, stream>>>(qb, kb, rl);
  k_vs   <<<dim3(2048),      256, 0, stream>>>(vb, rl, vs);
  hipMemsetAsync(ao, 0, (size_t)2097152 * 4, stream);
  k_attn2<<<dim3(64, 2, BB), 256, 0, stream>>>(qb, kb, vs, ao);
  // Xn overlaps qb/kb/vb/rl/vs -> zero only after k_attn2 (also zeroes guard ring)
  hipMemsetAsync(Xn, 0, (size_t)BB * 66 * 66 * 768 * 2, stream);
  k_proj <<<dim3(64, 2, BB), 256, 0, stream>>>(ao, tgt, Wp, bp, gamma, Xn);
  k_pack <<<dim3(64, 8, BB), 256, 0, stream>>>(prev, Xn);
  k_wb   <<<dim3(6912),      256, 0, stream>>>(Wc, Wb);
  k_conv_mfma<<<dim3(64, 2, BB), 256, 0, stream>>>(Xn, Wb, bcw, cb);
  k_inorm<<<dim3(1024),      256, 0, stream>>>(cb, (float*)d_out);
}

// Round 7
// 372.728 us; speedup vs baseline: 1.5792x; 1.0098x over previous
//
#include <hip/hip_runtime.h>
#include <hip/hip_bf16.h>

#define BB 4
#define CC 256
#define HW 4096
#define DD 128

typedef __attribute__((ext_vector_type(8))) short bf16x8;
typedef __attribute__((ext_vector_type(4))) short bf16x4;
typedef __attribute__((ext_vector_type(4))) float f32x4;
typedef __attribute__((ext_vector_type(4))) unsigned uint4v;

static __device__ __forceinline__ void ld4(float* dst, const float* src) {
  float4 t = *(const float4*)src;
  dst[0] = t.x; dst[1] = t.y; dst[2] = t.z; dst[3] = t.w;
}

// float -> bf16 (RNE) raw bits
static __device__ __forceinline__ short f2b(float f) {
  unsigned u = __float_as_uint(f);
  u += 0x7fffu + ((u >> 16) & 1u);
  return (short)(u >> 16);
}
static __device__ __forceinline__ unsigned pk2(float lo, float hi) {
  return (unsigned)(unsigned short)f2b(lo) | ((unsigned)(unsigned short)f2b(hi) << 16);
}

// async global->LDS DMA, 16B per lane; LDS dest must be linear in lane order
static __device__ __forceinline__ void gl16(const short* g, short* l) {
  __builtin_amdgcn_global_load_lds(
      (const __attribute__((address_space(1))) unsigned*)g,
      (__attribute__((address_space(3))) unsigned*)l, 16, 0, 0);
}

// ---------------- K1: q/k/v 1x1 conv as LDS-staged bf16 MFMA.
// Per (pxtile, which, b): GEMM W(128x256) @ X(256x64px).
// Outputs: q,k -> (B,HW,128) bf16 (pre-transposed for attention);
//          v   -> (B,128,HW) bf16.
__global__ __launch_bounds__(256) void k_qkv_mfma(
    const float* __restrict__ src, const float* __restrict__ tgt,
    const float* __restrict__ Wq, const float* __restrict__ bq,
    const float* __restrict__ Wk, const float* __restrict__ bk,
    const float* __restrict__ Wv, const float* __restrict__ bv,
    short* __restrict__ qb, short* __restrict__ kb, short* __restrict__ vb)
{
  __shared__ __align__(16) short Wt[128 * 40];  // [ch][c], stride 40 (2-way free)
  __shared__ __align__(16) short Xt[64 * 40];   // [px][c]
  __shared__ __align__(16) short T[9216];       // epilogue tile
  const int tid = threadIdx.x;
  const int wv = tid >> 6;
  const int lane = tid & 63;
  const int t = lane & 15, q = lane >> 4;
  const int px0 = blockIdx.x * 64;
  const int which = blockIdx.y;
  const int b = blockIdx.z;
  const float* X    = (which == 0) ? src : tgt;
  const float* Wm   = (which == 0) ? Wq : (which == 1) ? Wk : Wv;
  const float* bias = (which == 0) ? bq : (which == 1) ? bk : bv;

  const f32x4 zf = {0.f, 0.f, 0.f, 0.f};
  f32x4 acc[2][4];
#pragma unroll
  for (int mt = 0; mt < 2; ++mt)
#pragma unroll
    for (int nt = 0; nt < 4; ++nt) acc[mt][nt] = zf;

  for (int kk = 0; kk < CC; kk += 32) {
    __syncthreads();
    // stage W tile: 128 ch x 32 c (f32 -> bf16)
#pragma unroll
    for (int u = 0; u < 4; ++u) {
      int e = tid + (u << 8);
      int row = e >> 3, cq = (e & 7) * 4;
      float4 w4 = *(const float4*)&Wm[row * CC + kk + cq];
      unsigned* dst = (unsigned*)(Wt + row * 40 + cq);
      dst[0] = pk2(w4.x, w4.y);
      dst[1] = pk2(w4.z, w4.w);
    }
    // stage X tile transposed: 32 c x 64 px -> Xt[px][c]
#pragma unroll
    for (int u = 0; u < 2; ++u) {
      int e = tid + (u << 8);
      int c = e >> 4, p4 = (e & 15) * 4;
      float4 xv = *(const float4*)&X[((size_t)b * CC + kk + c) * HW + px0 + p4];
      Xt[(p4 + 0) * 40 + c] = f2b(xv.x);
      Xt[(p4 + 1) * 40 + c] = f2b(xv.y);
      Xt[(p4 + 2) * 40 + c] = f2b(xv.z);
      Xt[(p4 + 3) * 40 + c] = f2b(xv.w);
    }
    __syncthreads();
    bf16x8 af[2], bfr[4];
#pragma unroll
    for (int mt = 0; mt < 2; ++mt)
      af[mt] = *(const bf16x8*)(Wt + (wv * 32 + mt * 16 + t) * 40 + q * 8);
#pragma unroll
    for (int nt = 0; nt < 4; ++nt)
      bfr[nt] = *(const bf16x8*)(Xt + (nt * 16 + t) * 40 + q * 8);
#pragma unroll
    for (int mt = 0; mt < 2; ++mt)
#pragma unroll
      for (int nt = 0; nt < 4; ++nt)
        acc[mt][nt] = __builtin_amdgcn_mfma_f32_16x16x32_bf16(
            af[mt], bfr[nt], acc[mt][nt], 0, 0, 0);
  }
  __syncthreads();
  // D mapping (verified idiom): ch = wv*32 + mt*16 + q*4 + r, px = nt*16 + t
  if (which < 2) {
    // T[px][ch], stride 136 -> coalesced (B,HW,128) store
#pragma unroll
    for (int mt = 0; mt < 2; ++mt) {
      int chb = wv * 32 + mt * 16 + q * 4;
#pragma unroll
      for (int r = 0; r < 4; ++r) {
        float bv_ = bias[chb + r];
#pragma unroll
        for (int nt = 0; nt < 4; ++nt)
          T[(nt * 16 + t) * 136 + chb + r] = f2b(acc[mt][nt][r] + bv_);
      }
    }
    __syncthreads();
    short* out = (which == 0) ? qb : kb;
    int p = tid >> 2, cq = (tid & 3) * 32;
    short* gdst = out + ((size_t)b * HW + px0 + p) * DD + cq;
#pragma unroll
    for (int e2 = 0; e2 < 4; ++e2)
      *(uint4*)(gdst + e2 * 8) = *(const uint4*)(T + p * 136 + cq + e2 * 8);
  } else {
    // T[ch][px], stride 72 -> coalesced (B,128,HW) store
#pragma unroll
    for (int mt = 0; mt < 2; ++mt) {
      int chb = wv * 32 + mt * 16 + q * 4;
#pragma unroll
      for (int r = 0; r < 4; ++r) {
        float bv_ = bias[chb + r];
#pragma unroll
        for (int nt = 0; nt < 4; ++nt)
          T[(chb + r) * 72 + nt * 16 + t] = f2b(acc[mt][nt][r] + bv_);
      }
    }
    __syncthreads();
    int ch = tid >> 1, pq = (tid & 1) * 32;
    short* gdst = vb + ((size_t)b * DD + ch) * HW + px0 + pq;
#pragma unroll
    for (int e2 = 0; e2 < 4; ++e2)
      *(uint4*)(gdst + e2 * 8) = *(const uint4*)(T + ch * 72 + pq + e2 * 8);
  }
}

// ---------------- K2: pass1 MFMA partial sums: rl[j] += sum_{i in range} exp(s[i,j])
// i-range split x4 across blockIdx.y for occupancy; rl pre-zeroed.
__global__ __launch_bounds__(256) void k_lsum2(
    const short* __restrict__ qb, const short* __restrict__ kb,
    float* __restrict__ rl)
{
  __shared__ float lred[4][64];
  const int tid = threadIdx.x;
  const int w = tid >> 6;
  const int lane = tid & 63;
  const int t = lane & 15, q = lane >> 4;
  const int j0 = blockIdx.x * 64;
  const int ibeg = blockIdx.y * 1024;
  const int b = blockIdx.z;
  const short* qbb = qb + (size_t)b * HW * DD;
  const short* kbb = kb + (size_t)b * HW * DD;

  bf16x8 Bq[4][4];
#pragma unroll
  for (int nt = 0; nt < 4; ++nt)
#pragma unroll
    for (int kk = 0; kk < 4; ++kk)
      Bq[nt][kk] = *(const bf16x8*)(qbb + (size_t)(j0 + nt * 16 + t) * DD + kk * 32 + q * 8);

  float racc[4] = {0.f, 0.f, 0.f, 0.f};
  const f32x4 zf = {0.f, 0.f, 0.f, 0.f};

  for (int i = ibeg + w * 16; i < ibeg + 1024; i += 64) {
    bf16x8 Ak[4];
#pragma unroll
    for (int kk = 0; kk < 4; ++kk)
      Ak[kk] = *(const bf16x8*)(kbb + (size_t)(i + t) * DD + kk * 32 + q * 8);
#pragma unroll
    for (int nt = 0; nt < 4; ++nt) {
      f32x4 d = zf;
#pragma unroll
      for (int kk = 0; kk < 4; ++kk)
        d = __builtin_amdgcn_mfma_f32_16x16x32_bf16(Ak[kk], Bq[nt][kk], d, 0, 0, 0);
      racc[nt] += __expf(d[0]) + __expf(d[1]) + __expf(d[2]) + __expf(d[3]);
    }
  }
#pragma unroll
  for (int nt = 0; nt < 4; ++nt) {
    float r = racc[nt];
    r += __shfl_xor(r, 16);
    r += __shfl_xor(r, 32);
    if (q == 0) lred[w][nt * 16 + t] = r;
  }
  __syncthreads();
  if (tid < 64) {
    float sum = lred[0][tid] + lred[1][tid] + lred[2][tid] + lred[3][tid];
    atomicAdd(&rl[(size_t)b * HW + j0 + tid], sum);
  }
}

// ---------------- K2b: vs[c][j] = bf16( vb[c][j] / l_j )   (B,128,HW)
__global__ __launch_bounds__(256) void k_vs(
    const short* __restrict__ vb, const float* __restrict__ rl,
    short* __restrict__ vs)
{
  int id4 = (blockIdx.x * 256 + threadIdx.x) * 4;
  int j = id4 & (HW - 1);
  int b = id4 >> 19;
  uint2 pv = *(const uint2*)(vb + id4);
  float f0 = __uint_as_float(pv.x << 16);
  float f1 = __uint_as_float(pv.x & 0xffff0000u);
  float f2 = __uint_as_float(pv.y << 16);
  float f3 = __uint_as_float(pv.y & 0xffff0000u);
  const float* rlb = rl + (size_t)b * HW + j;
  unsigned u0 = pk2(f0 / rlb[0], f1 / rlb[1]);
  unsigned u1 = pk2(f2 / rlb[2], f3 / rlb[3]);
  *(uint2*)(vs + id4) = make_uint2(u0, u1);
}

// ---------------- K3: pass2, register-P (R6-verified) + LDS DOUBLE-BUFFER,
// ONE barrier per j-iter (was 2):
//   barrier -> ds_write tile n+1 into buf[cur^1] -> issue loads tile n+2
//           -> compute tile n from buf[cur]
// Writes and reads hit different buffers, so staging overlaps compute of
// other waves; barrier count 64 -> 32. T14 prefetch distance unchanged.
// LDS 35840 -> 71680 B; 2 blocks/CU still fit (143,360 <= 163,840).
__global__ __launch_bounds__(256, 2) void k_attn2(
    const short* __restrict__ qb, const short* __restrict__ kb,
    const short* __restrict__ vs, float* __restrict__ ao)
{
  __shared__ __align__(16) short Qs[2][64 * 136];   // [j][c], stride 136
  __shared__ __align__(16) short Vp[2][128 * 72];   // [c][kappa] permuted
  const int tid = threadIdx.x;
  const int w = tid >> 6;
  const int lane = tid & 63;
  const int t = lane & 15, q = lane >> 4;
  const int b = blockIdx.z;
  const int i0 = blockIdx.x * 64 + w * 16;
  const int jbeg = blockIdx.y * 2048, jend = jbeg + 2048;
  const short* qbb = qb + (size_t)b * HW * DD;
  const short* kbb = kb + (size_t)b * HW * DD;
  const short* vsb = vs + (size_t)b * DD * HW;
  const f32x4 zf = {0.f, 0.f, 0.f, 0.f};

  bf16x8 Ak[4];
#pragma unroll
  for (int kk = 0; kk < 4; ++kk)
    Ak[kk] = *(const bf16x8*)(kbb + (size_t)(i0 + t) * DD + kk * 32 + q * 8);

  f32x4 acc[8];
#pragma unroll
  for (int nt = 0; nt < 8; ++nt) acc[nt] = zf;

  bf16x8 rq[4], rv[4];
#define LOADT(jt)                                                             \
  {                                                                           \
    _Pragma("unroll")                                                         \
    for (int r = 0; r < 4; ++r) {                                             \
      int e = tid + (r << 8);                                                 \
      rq[r] = *(const bf16x8*)(qbb + (size_t)((jt) + (e >> 4)) * DD +         \
                               (e & 15) * 8);                                 \
      rv[r] = *(const bf16x8*)(vsb + (size_t)(e >> 3) * HW + (jt) +           \
                               (e & 7) * 8);                                  \
    }                                                                         \
  }
#define WRITET(buf)                                                           \
  {                                                                           \
    _Pragma("unroll")                                                         \
    for (int r = 0; r < 4; ++r) {                                             \
      int e = tid + (r << 8);                                                 \
      *(bf16x8*)(Qs[buf] + (e >> 4) * 136 + (e & 15) * 8) = rq[r];            \
    }                                                                         \
    _Pragma("unroll")                                                         \
    for (int r = 0; r < 4; ++r) {                                             \
      int e = tid + (r << 8);                                                 \
      int c = e >> 3, u8 = e & 7;                                             \
      int kap = (u8 >> 2) * 32 + (u8 & 1) * 16 + ((u8 >> 1) & 1) * 4;         \
      bf16x4 lo = __builtin_shufflevector(rv[r], rv[r], 0, 1, 2, 3);          \
      bf16x4 hi = __builtin_shufflevector(rv[r], rv[r], 4, 5, 6, 7);          \
      *(bf16x4*)(Vp[buf] + c * 72 + kap) = lo;                                \
      *(bf16x4*)(Vp[buf] + c * 72 + kap + 8) = hi;                            \
    }                                                                         \
  }

  // prologue: tile 0 -> regs -> buf0 ; tile 1 -> regs
  LOADT(jbeg);
  WRITET(0);
  LOADT(jbeg + 64);

  int cur = 0;
  for (int j = jbeg; j < jend; j += 64) {
    __syncthreads();  // buf[cur] writes visible; prior reads of buf[cur^1] done
    if (j + 64 < jend) {
      WRITET(cur ^ 1);               // tile j+64 from regs
      if (j + 128 < jend) LOADT(j + 128);  // T14: issue tile j+128
    }
    const short* Qb = Qs[cur];
    const short* Vb = Vp[cur];
    // S^T MFMA: sv[nt][r] = S[i0+t][j + nt*16 + q*4 + r]
    f32x4 sv[4];
#pragma unroll
    for (int nt = 0; nt < 4; ++nt) sv[nt] = zf;
#pragma unroll
    for (int nt = 0; nt < 4; ++nt)
#pragma unroll
      for (int kk = 0; kk < 4; ++kk) {
        bf16x8 bq = *(const bf16x8*)(Qb + (nt * 16 + t) * 136 + kk * 32 + q * 8);
        sv[nt] = __builtin_amdgcn_mfma_f32_16x16x32_bf16(bq, Ak[kk], sv[nt], 0, 0, 0);
      }
    // exp in-register + pack PV A-fragments (no LDS, no cross-lane)
    bf16x8 ap[2];
#pragma unroll
    for (int ks = 0; ks < 2; ++ks) {
      unsigned w0 = pk2(__expf(sv[2 * ks][0]), __expf(sv[2 * ks][1]));
      unsigned w1 = pk2(__expf(sv[2 * ks][2]), __expf(sv[2 * ks][3]));
      unsigned w2 = pk2(__expf(sv[2 * ks + 1][0]), __expf(sv[2 * ks + 1][1]));
      unsigned w3 = pk2(__expf(sv[2 * ks + 1][2]), __expf(sv[2 * ks + 1][3]));
      uint4v pw = {w0, w1, w2, w3};
      ap[ks] = __builtin_bit_cast(bf16x8, pw);
    }
    // PV: linear b128 reads from permuted Vp
#pragma unroll
    for (int nt = 0; nt < 8; ++nt)
#pragma unroll
      for (int ks = 0; ks < 2; ++ks) {
        bf16x8 bv = *(const bf16x8*)(Vb + (nt * 16 + t) * 72 + ks * 32 + q * 8);
        acc[nt] = __builtin_amdgcn_mfma_f32_16x16x32_bf16(ap[ks], bv, acc[nt], 0, 0, 0);
      }
    cur ^= 1;
  }
#undef LOADT
#undef WRITET
  float* aob = ao + (size_t)b * DD * HW;
#pragma unroll
  for (int nt = 0; nt < 8; ++nt)
#pragma unroll
    for (int r = 0; r < 4; ++r)
      atomicAdd(&aob[(size_t)(nt * 16 + t) * HW + i0 + q * 4 + r], acc[nt][r]);
}

// ---------------- K4: y = tgt + gamma*(Wp@ao + bp) -> Xn interior, ch [0,256)
// Xn layout: (B, 66, 66, 768) NHWC bf16 with a zeroed guard ring.
__global__ __launch_bounds__(256) void k_proj(
    const float* __restrict__ ao, const float* __restrict__ tgt,
    const float* __restrict__ Wp, const float* __restrict__ bp,
    const float* __restrict__ gamma, short* __restrict__ Xn)
{
  __shared__ float Wt[32][132];
  __shared__ float Xs[32][68];
  __shared__ float T[64][133];
  const int tid = threadIdx.x;
  const int tx = tid & 15, ty = tid >> 4;
  const int p0 = blockIdx.x * 64;
  const int ro = blockIdx.y * 128;
  const int b = blockIdx.z;
  const float g0 = gamma[0];

  float acc[8][4];
#pragma unroll
  for (int i = 0; i < 8; ++i)
#pragma unroll
    for (int j = 0; j < 4; ++j) acc[i][j] = 0.f;

  for (int kk = 0; kk < DD; kk += 32) {
    __syncthreads();
#pragma unroll
    for (int u = 0; u < 4; ++u) {
      int e = tid + 256 * u;
      int c4 = (e & 7) * 4, r = e >> 3;
      float w[4]; ld4(w, &Wp[(ro + r) * DD + kk + c4]);
      Wt[c4 + 0][r] = w[0]; Wt[c4 + 1][r] = w[1];
      Wt[c4 + 2][r] = w[2]; Wt[c4 + 3][r] = w[3];
    }
#pragma unroll
    for (int u = 0; u < 2; ++u) {
      int e = tid + 256 * u;
      int p4 = (e & 15) * 4, c = e >> 4;
      *(float4*)&Xs[c][p4] = *(const float4*)&ao[(b * DD + kk + c) * HW + p0 + p4];
    }
    __syncthreads();
#pragma unroll 4
    for (int c = 0; c < 32; ++c) {
      float wa[8], xb[4];
      ld4(wa, &Wt[c][ty * 8]); ld4(wa + 4, &Wt[c][ty * 8 + 4]);
      ld4(xb, &Xs[c][tx * 4]);
#pragma unroll
      for (int rr = 0; rr < 8; ++rr)
#pragma unroll
        for (int pp = 0; pp < 4; ++pp) acc[rr][pp] += wa[rr] * xb[pp];
    }
  }
#pragma unroll
  for (int rr = 0; rr < 8; ++rr) {
    int r = ro + ty * 8 + rr;
    int idx = (b * CC + r) * HW + p0 + tx * 4;
    float4 t4 = *(const float4*)&tgt[idx];
    float bpv = bp[r];
    T[tx * 4 + 0][ty * 8 + rr] = t4.x + g0 * (acc[rr][0] + bpv);
    T[tx * 4 + 1][ty * 8 + rr] = t4.y + g0 * (acc[rr][1] + bpv);
    T[tx * 4 + 2][ty * 8 + rr] = t4.z + g0 * (acc[rr][2] + bpv);
    T[tx * 4 + 3][ty * 8 + rr] = t4.w + g0 * (acc[rr][3] + bpv);
  }
  __syncthreads();
  {
    int p = tid >> 2, cq = (tid & 3) * 32;
    int h = p0 >> 6;
    unsigned* dst = (unsigned*)(Xn + ((((size_t)b * 66 + h + 1) * 66) + 1 + p) * 768 + ro + cq);
#pragma unroll
    for (int e = 0; e < 16; ++e)
      dst[e] = pk2(T[p][cq + 2 * e], T[p][cq + 2 * e + 1]);
  }
}

// ---------------- K4b: upsample prev into Xn interior, channels [256,768)
__global__ __launch_bounds__(256) void k_pack(
    const float* __restrict__ prev, short* __restrict__ Xn)
{
  __shared__ float tile[64][65];
  const int tid = threadIdx.x;
  const int h = blockIdx.x;
  const int ci0 = blockIdx.y * 64;
  const int b = blockIdx.z;

  {
    int w = tid & 63, r = tid >> 6;
    for (int cs = r; cs < 64; cs += 4)
      tile[cs][w] = prev[((size_t)b * 512 + ci0 + cs) * 1024 + (h >> 1) * 32 + (w >> 1)];
  }
  __syncthreads();
  {
    int ci = tid & 63, wq = tid >> 6;
    for (int ws2 = wq; ws2 < 64; ws2 += 4)
      Xn[((((size_t)b * 66 + h + 1) * 66) + 1 + ws2) * 768 + 256 + ci0 + ci] = f2b(tile[ci][ws2]);
  }
}

// ---------------- K4c: weight repack Wc(256,768,3,3) f32 -> Wb(256,9,768) bf16
__global__ __launch_bounds__(256) void k_wb(
    const float* __restrict__ Wc, short* __restrict__ Wb)
{
  int i = blockIdx.x * 256 + threadIdx.x;
  int o = i / 6912;
  int rem = i - o * 6912;
  int khw = rem / 768;
  int ci = rem - khw * 768;
  Wb[i] = f2b(Wc[(size_t)o * 6912 + ci * 9 + khw]);
}

// ---------------- K5: 3x3 conv, R2 structure (64x2x4 grid, 2 blocks/CU,
// 2 barriers/stage) with staging switched to global_load_lds DMA:
// no VGPR round-trip, no ds_write instructions, no staging VALU.
// LDS tiles are LINEAR stride-64 (DMA requires lane-linear dest); the
// 128B-row read conflict is broken by a both-sides XOR involution:
//   LDS slot (row, g) <- global granule (g ^ (row&7));
//   read granule G at slot (G ^ (row&7)).
// Operand values are bit-identical to R2 -> epilogue mapping unchanged.
__global__ __launch_bounds__(256, 2) void k_conv_mfma(
    const short* __restrict__ Xn,   // (B,66,66,768) bf16, guard ring zero
    const short* __restrict__ Wb,   // (256,9,768) bf16
    const float* __restrict__ bcw,
    short* __restrict__ cb)         // (B,256,4096) bf16
{
  __shared__ __align__(16) short Wl[384 * 64];  // 48 KB, [kw*128+cout][64ci]
  __shared__ __align__(16) short Xl[66 * 64];   // 8.25 KB, [px][64ci]
  const int tid = threadIdx.x;
  const int wv = tid >> 6;
  const int lane = tid & 63;
  const int t = lane & 15, q = lane >> 4;
  const int h = blockIdx.x;
  const int m0blk = blockIdx.y * 128;
  const int b = blockIdx.z;

  const f32x4 zf = {0.f, 0.f, 0.f, 0.f};
  f32x4 acc[2][4];
#pragma unroll
  for (int mt = 0; mt < 2; ++mt)
#pragma unroll
    for (int nt = 0; nt < 4; ++nt) acc[mt][nt] = zf;

  for (int kh = 0; kh < 3; ++kh) {
    const short* wsrc = Wb + (size_t)m0blk * 6912 + (kh * 3) * 768;
    const short* xsrc = Xn + ((size_t)b * 66 + h + kh) * 66 * 768;
    for (int ci0 = 0; ci0 < 768; ci0 += 64) {
      // stage W: 384 rows x 8 granules(16B) = 3072; 12 DMA per thread
#pragma unroll
      for (int r = 0; r < 12; ++r) {
        int e = tid + (r << 8);
        int g = e & 7, row = e >> 3;
        int kw = row >> 7, cout = row & 127;
        int gs = g ^ (row & 7);
        gl16(wsrc + (size_t)cout * 6912 + kw * 768 + ci0 + gs * 8, Wl + e * 8);
      }
      // stage X: 66 rows x 8 granules = 528
#pragma unroll
      for (int r = 0; r < 3; ++r) {
        int e = tid + (r << 8);
        if (e < 528) {
          int g = e & 7, px = e >> 3;
          int gs = g ^ (px & 7);
          gl16(xsrc + (size_t)px * 768 + ci0 + gs * 8, Xl + e * 8);
        }
      }
      __syncthreads();
#pragma unroll
      for (int kw = 0; kw < 3; ++kw) {
        bf16x8 af[2][2], bfr[4][2];
#pragma unroll
        for (int kk = 0; kk < 2; ++kk) {
#pragma unroll
          for (int mt = 0; mt < 2; ++mt) {
            int row = kw * 128 + wv * 32 + mt * 16 + t;
            int g = (kk * 4 + q) ^ (row & 7);
            af[mt][kk] = *(const bf16x8*)(Wl + row * 64 + g * 8);
          }
#pragma unroll
          for (int nt = 0; nt < 4; ++nt) {
            int row = nt * 16 + t + kw;
            int g = (kk * 4 + q) ^ (row & 7);
            bfr[nt][kk] = *(const bf16x8*)(Xl + row * 64 + g * 8);
          }
        }
#pragma unroll
        for (int kk = 0; kk < 2; ++kk)
#pragma unroll
          for (int mt = 0; mt < 2; ++mt)
#pragma unroll
            for (int nt = 0; nt < 4; ++nt)
              acc[mt][nt] = __builtin_amdgcn_mfma_f32_16x16x32_bf16(
                  af[mt][kk], bfr[nt][kk], acc[mt][nt], 0, 0, 0);
      }
      __syncthreads();
    }
  }
  // D mapping: outch = m0blk + wv*32 + mt*16 + q*4 + r ; px = nt*16 + t
#pragma unroll
  for (int mt = 0; mt < 2; ++mt) {
    int om = m0blk + wv * 32 + mt * 16 + q * 4;
#pragma unroll
    for (int r = 0; r < 4; ++r) {
      float bias = bcw[om + r];
      short* orow = cb + ((size_t)b * CC + om + r) * HW + h * 64;
#pragma unroll
      for (int nt = 0; nt < 4; ++nt)
        orow[nt * 16 + t] = f2b(acc[mt][nt][r] + bias);
    }
  }
}

// ---------------- K6: InstanceNorm (biased var, eps=1e-5) + ReLU; bf16 in, f32 out
__global__ __launch_bounds__(256) void k_inorm(
    const short* __restrict__ cb, float* __restrict__ out)
{
  __shared__ float buf[4096];
  __shared__ float red[8];
  const int tid = threadIdx.x;
  const int ch = blockIdx.x;
  const short* srcp = cb + (size_t)ch * HW;

  float s = 0.f, sq = 0.f;
#pragma unroll
  for (int u = 0; u < 2; ++u) {
    int sidx = u * 2048 + tid * 8;
    uint4 pk = *(const uint4*)(srcp + sidx);
    float f[8];
    f[0] = __uint_as_float(pk.x << 16); f[1] = __uint_as_float(pk.x & 0xffff0000u);
    f[2] = __uint_as_float(pk.y << 16); f[3] = __uint_as_float(pk.y & 0xffff0000u);
    f[4] = __uint_as_float(pk.z << 16); f[5] = __uint_as_float(pk.z & 0xffff0000u);
    f[6] = __uint_as_float(pk.w << 16); f[7] = __uint_as_float(pk.w & 0xffff0000u);
#pragma unroll
    for (int e = 0; e < 8; ++e) {
      buf[sidx + e] = f[e];
      s += f[e];
      sq += f[e] * f[e];
    }
  }
#pragma unroll
  for (int m = 32; m >= 1; m >>= 1) {
    s  += __shfl_xor(s, m, 64);
    sq += __shfl_xor(sq, m, 64);
  }
  if ((tid & 63) == 0) { red[tid >> 6] = s; red[4 + (tid >> 6)] = sq; }
  __syncthreads();
  if (tid == 0) {
    float S = red[0] + red[1] + red[2] + red[3];
    float Q = red[4] + red[5] + red[6] + red[7];
    float mean = S * (1.f / HW);
    float var = Q * (1.f / HW) - mean * mean;
    red[0] = mean;
    red[1] = rsqrtf(var + 1e-5f);
  }
  __syncthreads();
  const float mean = red[0], rs = red[1];
#pragma unroll
  for (int u = 0; u < 4; ++u) {
    int idx = u * 1024 + tid * 4;
    float4 v = *(const float4*)&buf[idx];
    float4 o4 = make_float4(fmaxf((v.x - mean) * rs, 0.f),
                            fmaxf((v.y - mean) * rs, 0.f),
                            fmaxf((v.z - mean) * rs, 0.f),
                            fmaxf((v.w - mean) * rs, 0.f));
    *(float4*)&out[(size_t)ch * HW + idx] = o4;
  }
}

extern "C" void kernel_launch(void* const* d_in, const int* in_sizes, int n_in,
                              void* d_out, int out_size, void* d_ws, size_t ws_size,
                              hipStream_t stream) {
  const float* src  = (const float*)d_in[0];
  const float* tgt  = (const float*)d_in[1];
  const float* prev = (const float*)d_in[2];
  const float* Wq = (const float*)d_in[3];  const float* bq = (const float*)d_in[4];
  const float* Wk = (const float*)d_in[5];  const float* bk = (const float*)d_in[6];
  const float* Wv = (const float*)d_in[7];  const float* bv = (const float*)d_in[8];
  const float* Wp = (const float*)d_in[9];  const float* bp = (const float*)d_in[10];
  const float* gamma = (const float*)d_in[11];
  const float* Wc = (const float*)d_in[12]; const float* bcw = (const float*)d_in[13];

  float* ws = (float*)d_ws;
  // float-unit offsets; lifetimes:
  short* qb = (short*)ws;                 // [0, 1048576)        dead after k_attn2
  short* kb = (short*)(ws + 1048576);     // [1048576, 2097152)  dead after k_attn2
  short* vb = (short*)(ws + 2097152);     // [2097152, 3145728)  dead after k_vs
  float* rl = ws + 3145728;               // [3145728, 3162112)  dead after k_vs
  short* vs = (short*)(ws + 3162112);     // [3162112, 4210688)  dead after k_attn2
  short* Xn = (short*)ws;                 // [0, 6690816)  (B,66,66,768) over qb/kb/vb/rl/vs
  float* ao = ws + 6690816;               // [6690816, 8787968)  zeroed before attn2
  short* cb = (short*)(ws + 6690816);     // over ao (ao dead after k_proj)
  short* Wb = (short*)(ws + 8787968);     // [8787968, 9672704)
  // high-water: 9,672,704 floats = 38.7 MB

  k_qkv_mfma<<<dim3(64, 3, BB), 256, 0, stream>>>(src, tgt, Wq, bq, Wk, bk, Wv, bv, qb, kb, vb);
  hipMemsetAsync(rl, 0, (size_t)BB * HW * 4, stream);
  k_lsum2<<<dim3(64, 4, BB), 256, 0, stream>>>(qb, kb, rl);
  k_vs   <<<dim3(2048),      256, 0, stream>>>(vb, rl, vs);
  hipMemsetAsync(ao, 0, (size_t)2097152 * 4, stream);
  k_attn2<<<dim3(64, 2, BB), 256, 0, stream>>>(qb, kb, vs, ao);
  // Xn overlaps qb/kb/vb/rl/vs -> zero only after k_attn2 (also zeroes guard ring)
  hipMemsetAsync(Xn, 0, (size_t)BB * 66 * 66 * 768 * 2, stream);
  k_proj <<<dim3(64, 2, BB), 256, 0, stream>>>(ao, tgt, Wp, bp, gamma, Xn);
  k_pack <<<dim3(64, 8, BB), 256, 0, stream>>>(prev, Xn);
  k_wb   <<<dim3(6912),      256, 0, stream>>>(Wc, Wb);
  k_conv_mfma<<<dim3(64, 2, BB), 256, 0, stream>>>(Xn, Wb, bcw, cb);
  k_inorm<<<dim3(1024),      256, 0, stream>>>(cb, (float*)d_out);
}

// Round 8
// 336.344 us; speedup vs baseline: 1.7501x; 1.1082x over previous
//
#include <hip/hip_runtime.h>
#include <hip/hip_bf16.h>

#define BB 4
#define CC 256
#define HW 4096
#define DD 128

typedef __attribute__((ext_vector_type(8))) short bf16x8;
typedef __attribute__((ext_vector_type(4))) short bf16x4;
typedef __attribute__((ext_vector_type(4))) float f32x4;
typedef __attribute__((ext_vector_type(16))) float f32x16;
typedef __attribute__((ext_vector_type(4))) unsigned uint4v;

static __device__ __forceinline__ void ld4(float* dst, const float* src) {
  float4 t = *(const float4*)src;
  dst[0] = t.x; dst[1] = t.y; dst[2] = t.z; dst[3] = t.w;
}

// float -> bf16 (RNE) raw bits
static __device__ __forceinline__ short f2b(float f) {
  unsigned u = __float_as_uint(f);
  u += 0x7fffu + ((u >> 16) & 1u);
  return (short)(u >> 16);
}
static __device__ __forceinline__ unsigned pk2(float lo, float hi) {
  return (unsigned)(unsigned short)f2b(lo) | ((unsigned)(unsigned short)f2b(hi) << 16);
}

// async global->LDS DMA, 16B per lane; LDS dest must be linear in lane order
static __device__ __forceinline__ void gl16(const short* g, short* l) {
  __builtin_amdgcn_global_load_lds(
      (const __attribute__((address_space(1))) unsigned*)g,
      (__attribute__((address_space(3))) unsigned*)l, 16, 0, 0);
}

// ---------------- K1: q/k/v 1x1 conv as LDS-staged bf16 MFMA.
// Per (pxtile, which, b): GEMM W(128x256) @ X(256x64px).
// Outputs: q,k -> (B,HW,128) bf16 (pre-transposed for attention);
//          v   -> (B,128,HW) bf16.
__global__ __launch_bounds__(256) void k_qkv_mfma(
    const float* __restrict__ src, const float* __restrict__ tgt,
    const float* __restrict__ Wq, const float* __restrict__ bq,
    const float* __restrict__ Wk, const float* __restrict__ bk,
    const float* __restrict__ Wv, const float* __restrict__ bv,
    short* __restrict__ qb, short* __restrict__ kb, short* __restrict__ vb)
{
  __shared__ __align__(16) short Wt[128 * 40];  // [ch][c], stride 40 (2-way free)
  __shared__ __align__(16) short Xt[64 * 40];   // [px][c]
  __shared__ __align__(16) short T[9216];       // epilogue tile
  const int tid = threadIdx.x;
  const int wv = tid >> 6;
  const int lane = tid & 63;
  const int t = lane & 15, q = lane >> 4;
  const int px0 = blockIdx.x * 64;
  const int which = blockIdx.y;
  const int b = blockIdx.z;
  const float* X    = (which == 0) ? src : tgt;
  const float* Wm   = (which == 0) ? Wq : (which == 1) ? Wk : Wv;
  const float* bias = (which == 0) ? bq : (which == 1) ? bk : bv;

  const f32x4 zf = {0.f, 0.f, 0.f, 0.f};
  f32x4 acc[2][4];
#pragma unroll
  for (int mt = 0; mt < 2; ++mt)
#pragma unroll
    for (int nt = 0; nt < 4; ++nt) acc[mt][nt] = zf;

  for (int kk = 0; kk < CC; kk += 32) {
    __syncthreads();
    // stage W tile: 128 ch x 32 c (f32 -> bf16)
#pragma unroll
    for (int u = 0; u < 4; ++u) {
      int e = tid + (u << 8);
      int row = e >> 3, cq = (e & 7) * 4;
      float4 w4 = *(const float4*)&Wm[row * CC + kk + cq];
      unsigned* dst = (unsigned*)(Wt + row * 40 + cq);
      dst[0] = pk2(w4.x, w4.y);
      dst[1] = pk2(w4.z, w4.w);
    }
    // stage X tile transposed: 32 c x 64 px -> Xt[px][c]
#pragma unroll
    for (int u = 0; u < 2; ++u) {
      int e = tid + (u << 8);
      int c = e >> 4, p4 = (e & 15) * 4;
      float4 xv = *(const float4*)&X[((size_t)b * CC + kk + c) * HW + px0 + p4];
      Xt[(p4 + 0) * 40 + c] = f2b(xv.x);
      Xt[(p4 + 1) * 40 + c] = f2b(xv.y);
      Xt[(p4 + 2) * 40 + c] = f2b(xv.z);
      Xt[(p4 + 3) * 40 + c] = f2b(xv.w);
    }
    __syncthreads();
    bf16x8 af[2], bfr[4];
#pragma unroll
    for (int mt = 0; mt < 2; ++mt)
      af[mt] = *(const bf16x8*)(Wt + (wv * 32 + mt * 16 + t) * 40 + q * 8);
#pragma unroll
    for (int nt = 0; nt < 4; ++nt)
      bfr[nt] = *(const bf16x8*)(Xt + (nt * 16 + t) * 40 + q * 8);
#pragma unroll
    for (int mt = 0; mt < 2; ++mt)
#pragma unroll
      for (int nt = 0; nt < 4; ++nt)
        acc[mt][nt] = __builtin_amdgcn_mfma_f32_16x16x32_bf16(
            af[mt], bfr[nt], acc[mt][nt], 0, 0, 0);
  }
  __syncthreads();
  // D mapping (verified idiom): ch = wv*32 + mt*16 + q*4 + r, px = nt*16 + t
  if (which < 2) {
    // T[px][ch], stride 136 -> coalesced (B,HW,128) store
#pragma unroll
    for (int mt = 0; mt < 2; ++mt) {
      int chb = wv * 32 + mt * 16 + q * 4;
#pragma unroll
      for (int r = 0; r < 4; ++r) {
        float bv_ = bias[chb + r];
#pragma unroll
        for (int nt = 0; nt < 4; ++nt)
          T[(nt * 16 + t) * 136 + chb + r] = f2b(acc[mt][nt][r] + bv_);
      }
    }
    __syncthreads();
    short* out = (which == 0) ? qb : kb;
    int p = tid >> 2, cq = (tid & 3) * 32;
    short* gdst = out + ((size_t)b * HW + px0 + p) * DD + cq;
#pragma unroll
    for (int e2 = 0; e2 < 4; ++e2)
      *(uint4*)(gdst + e2 * 8) = *(const uint4*)(T + p * 136 + cq + e2 * 8);
  } else {
    // T[ch][px], stride 72 -> coalesced (B,128,HW) store
#pragma unroll
    for (int mt = 0; mt < 2; ++mt) {
      int chb = wv * 32 + mt * 16 + q * 4;
#pragma unroll
      for (int r = 0; r < 4; ++r) {
        float bv_ = bias[chb + r];
#pragma unroll
        for (int nt = 0; nt < 4; ++nt)
          T[(chb + r) * 72 + nt * 16 + t] = f2b(acc[mt][nt][r] + bv_);
      }
    }
    __syncthreads();
    int ch = tid >> 1, pq = (tid & 1) * 32;
    short* gdst = vb + ((size_t)b * DD + ch) * HW + px0 + pq;
#pragma unroll
    for (int e2 = 0; e2 < 4; ++e2)
      *(uint4*)(gdst + e2 * 8) = *(const uint4*)(T + ch * 72 + pq + e2 * 8);
  }
}

// ---------------- K2: pass1 MFMA partial sums: rl[j] += sum_{i in range} exp(s[i,j])
// i-range split x4 across blockIdx.y for occupancy; rl pre-zeroed.
__global__ __launch_bounds__(256) void k_lsum2(
    const short* __restrict__ qb, const short* __restrict__ kb,
    float* __restrict__ rl)
{
  __shared__ float lred[4][64];
  const int tid = threadIdx.x;
  const int w = tid >> 6;
  const int lane = tid & 63;
  const int t = lane & 15, q = lane >> 4;
  const int j0 = blockIdx.x * 64;
  const int ibeg = blockIdx.y * 1024;
  const int b = blockIdx.z;
  const short* qbb = qb + (size_t)b * HW * DD;
  const short* kbb = kb + (size_t)b * HW * DD;

  bf16x8 Bq[4][4];
#pragma unroll
  for (int nt = 0; nt < 4; ++nt)
#pragma unroll
    for (int kk = 0; kk < 4; ++kk)
      Bq[nt][kk] = *(const bf16x8*)(qbb + (size_t)(j0 + nt * 16 + t) * DD + kk * 32 + q * 8);

  float racc[4] = {0.f, 0.f, 0.f, 0.f};
  const f32x4 zf = {0.f, 0.f, 0.f, 0.f};

  for (int i = ibeg + w * 16; i < ibeg + 1024; i += 64) {
    bf16x8 Ak[4];
#pragma unroll
    for (int kk = 0; kk < 4; ++kk)
      Ak[kk] = *(const bf16x8*)(kbb + (size_t)(i + t) * DD + kk * 32 + q * 8);
#pragma unroll
    for (int nt = 0; nt < 4; ++nt) {
      f32x4 d = zf;
#pragma unroll
      for (int kk = 0; kk < 4; ++kk)
        d = __builtin_amdgcn_mfma_f32_16x16x32_bf16(Ak[kk], Bq[nt][kk], d, 0, 0, 0);
      racc[nt] += __expf(d[0]) + __expf(d[1]) + __expf(d[2]) + __expf(d[3]);
    }
  }
#pragma unroll
  for (int nt = 0; nt < 4; ++nt) {
    float r = racc[nt];
    r += __shfl_xor(r, 16);
    r += __shfl_xor(r, 32);
    if (q == 0) lred[w][nt * 16 + t] = r;
  }
  __syncthreads();
  if (tid < 64) {
    float sum = lred[0][tid] + lred[1][tid] + lred[2][tid] + lred[3][tid];
    atomicAdd(&rl[(size_t)b * HW + j0 + tid], sum);
  }
}

// ---------------- K2b: vs[c][j] = bf16( vb[c][j] / l_j )   (B,128,HW)
__global__ __launch_bounds__(256) void k_vs(
    const short* __restrict__ vb, const float* __restrict__ rl,
    short* __restrict__ vs)
{
  int id4 = (blockIdx.x * 256 + threadIdx.x) * 4;
  int j = id4 & (HW - 1);
  int b = id4 >> 19;
  uint2 pv = *(const uint2*)(vb + id4);
  float f0 = __uint_as_float(pv.x << 16);
  float f1 = __uint_as_float(pv.x & 0xffff0000u);
  float f2 = __uint_as_float(pv.y << 16);
  float f3 = __uint_as_float(pv.y & 0xffff0000u);
  const float* rlb = rl + (size_t)b * HW + j;
  unsigned u0 = pk2(f0 / rlb[0], f1 / rlb[1]);
  unsigned u1 = pk2(f2 / rlb[2], f3 / rlb[3]);
  *(uint2*)(vs + id4) = make_uint2(u0, u1);
}

// ---------------- K3: pass2, 32x32x16 MFMA restructure (2x FLOP per LDS read).
// Wave = 32 i x 64 j per iter; block = 128 i (4 waves); grid (32, 4, B).
// S^T = mfma(A=Q, B=K): D col = lane&31 = i (m74/m101 layout), rows = j over
// regs -> lane holds full P-row slice for its own i, in registers.
// PV K-axis perm is the j<->k bit-swap (bits 2,3), folded into V-staging:
//   thread's 8 contiguous j's land at kap, kap+8;
//   kap = (u8>>2)*32 + ((u8>>1)&1)*16 + (u8&1)*4.
// Qs uses a 4-bit XOR granule swizzle (slot = g ^ (row&15), both sides) so
// the 32-row A-frag column reads are 2-way (free). Vp stride 72 (4-way, ok).
// ao is now [B][HW][DD] (i-major) so epilogue atomics are 128B-contiguous.
// Double-buffer + single barrier + T14 prefetch as R7.
__global__ __launch_bounds__(256, 2) void k_attn2(
    const short* __restrict__ qb, const short* __restrict__ kb,
    const short* __restrict__ vs, float* __restrict__ ao)
{
  __shared__ __align__(16) short Qs[2][64 * 128];   // [j][xor-swizzled c-granules]
  __shared__ __align__(16) short Vp[2][128 * 72];   // [c][kappa] permuted
  const int tid = threadIdx.x;
  const int w = tid >> 6;
  const int lane = tid & 63;
  const int l31 = lane & 31, h = lane >> 5;
  const int b = blockIdx.z;
  const int i0w = blockIdx.x * 128 + w * 32;
  const int jbeg = blockIdx.y * 1024, jend = jbeg + 1024;
  const short* qbb = qb + (size_t)b * HW * DD;
  const short* kbb = kb + (size_t)b * HW * DD;
  const short* vsb = vs + (size_t)b * DD * HW;

  // K fragments (global, loaded once): B[k=c][n=i]: lane holds i = i0w+l31,
  // c = kk*16 + h*8 + u
  bf16x8 Bk[8];
#pragma unroll
  for (int kk = 0; kk < 8; ++kk)
    Bk[kk] = *(const bf16x8*)(kbb + (size_t)(i0w + l31) * DD + kk * 16 + h * 8);

  f32x16 acc[4];
#pragma unroll
  for (int nt = 0; nt < 4; ++nt)
#pragma unroll
    for (int e = 0; e < 16; ++e) acc[nt][e] = 0.f;

  bf16x8 rq[4], rv[4];
#define LOADT(jt)                                                             \
  {                                                                           \
    _Pragma("unroll")                                                         \
    for (int r = 0; r < 4; ++r) {                                             \
      int e = tid + (r << 8);                                                 \
      rq[r] = *(const bf16x8*)(qbb + (size_t)((jt) + (e >> 4)) * DD +         \
                               (e & 15) * 8);                                 \
      rv[r] = *(const bf16x8*)(vsb + (size_t)(e >> 3) * HW + (jt) +           \
                               (e & 7) * 8);                                  \
    }                                                                         \
  }
#define WRITET(buf)                                                           \
  {                                                                           \
    _Pragma("unroll")                                                         \
    for (int r = 0; r < 4; ++r) {                                             \
      int e = tid + (r << 8);                                                 \
      int row = e >> 4;                                                       \
      int slot = (e & 15) ^ (row & 15);                                       \
      *(bf16x8*)(Qs[buf] + row * 128 + slot * 8) = rq[r];                     \
    }                                                                         \
    _Pragma("unroll")                                                         \
    for (int r = 0; r < 4; ++r) {                                             \
      int e = tid + (r << 8);                                                 \
      int c = e >> 3, u8 = e & 7;                                             \
      int kap = (u8 >> 2) * 32 + ((u8 >> 1) & 1) * 16 + (u8 & 1) * 4;         \
      bf16x4 lo = __builtin_shufflevector(rv[r], rv[r], 0, 1, 2, 3);          \
      bf16x4 hi = __builtin_shufflevector(rv[r], rv[r], 4, 5, 6, 7);          \
      *(bf16x4*)(Vp[buf] + c * 72 + kap) = lo;                                \
      *(bf16x4*)(Vp[buf] + c * 72 + kap + 8) = hi;                            \
    }                                                                         \
  }

  // prologue: tile 0 -> regs -> buf0 ; tile 1 -> regs
  LOADT(jbeg);
  WRITET(0);
  LOADT(jbeg + 64);

  int cur = 0;
  for (int j = jbeg; j < jend; j += 64) {
    __syncthreads();  // buf[cur] writes visible; prior reads of buf[cur^1] done
    if (j + 64 < jend) {
      WRITET(cur ^ 1);
      if (j + 128 < jend) LOADT(j + 128);
    }
    const short* Qb = Qs[cur];
    const short* Vb = Vp[cur];
    // S^T: sv[ntj] lane holds S[i0w+l31][j + (reg&3)+8*(reg>>2)+4h+32*ntj]
    f32x16 sv[2];
#pragma unroll
    for (int ntj = 0; ntj < 2; ++ntj)
#pragma unroll
      for (int e = 0; e < 16; ++e) sv[ntj][e] = 0.f;
#pragma unroll
    for (int ntj = 0; ntj < 2; ++ntj)
#pragma unroll
      for (int kk = 0; kk < 8; ++kk) {
        int row = ntj * 32 + l31;
        int slot = (kk * 2 + h) ^ (row & 15);
        bf16x8 aq = *(const bf16x8*)(Qb + row * 128 + slot * 8);
        sv[ntj] = __builtin_amdgcn_mfma_f32_32x32x16_bf16(aq, Bk[kk], sv[ntj], 0, 0, 0);
      }
    // exp + pack PV A-frags: ap[s][u] = bf16(exp(sv[s>>1][(s&1)*8+u]))
    bf16x8 ap[4];
#pragma unroll
    for (int s = 0; s < 4; ++s) {
      const int tI = s >> 1, base = (s & 1) * 8;
      unsigned w0 = pk2(__expf(sv[tI][base + 0]), __expf(sv[tI][base + 1]));
      unsigned w1 = pk2(__expf(sv[tI][base + 2]), __expf(sv[tI][base + 3]));
      unsigned w2 = pk2(__expf(sv[tI][base + 4]), __expf(sv[tI][base + 5]));
      unsigned w3 = pk2(__expf(sv[tI][base + 6]), __expf(sv[tI][base + 7]));
      uint4v pw = {w0, w1, w2, w3};
      ap[s] = __builtin_bit_cast(bf16x8, pw);
    }
    // PV: out[32i x 128c] += P @ Vp ; B-frag = linear b128 from Vp
#pragma unroll
    for (int ntc = 0; ntc < 4; ++ntc)
#pragma unroll
      for (int s = 0; s < 4; ++s) {
        bf16x8 bv = *(const bf16x8*)(Vb + (ntc * 32 + l31) * 72 + s * 16 + h * 8);
        acc[ntc] = __builtin_amdgcn_mfma_f32_32x32x16_bf16(ap[s], bv, acc[ntc], 0, 0, 0);
      }
    cur ^= 1;
  }
#undef LOADT
#undef WRITET
  // epilogue: ao is [B][HW][DD]; D row i = (rg&3)+8*(rg>>2)+4h, col c = ntc*32+l31
  float* aob = ao + (size_t)b * HW * DD;
#pragma unroll
  for (int ntc = 0; ntc < 4; ++ntc)
#pragma unroll
    for (int rg = 0; rg < 16; ++rg) {
      int i = i0w + (rg & 3) + 8 * (rg >> 2) + 4 * h;
      atomicAdd(&aob[(size_t)i * DD + ntc * 32 + l31], acc[ntc][rg]);
    }
}

// ---------------- K4: y = tgt + gamma*(Wp@ao + bp) -> Xn interior, ch [0,256)
// ao is [B][HW][DD] (i-major). Xn layout: (B,66,66,768) NHWC bf16, guard ring.
__global__ __launch_bounds__(256) void k_proj(
    const float* __restrict__ ao, const float* __restrict__ tgt,
    const float* __restrict__ Wp, const float* __restrict__ bp,
    const float* __restrict__ gamma, short* __restrict__ Xn)
{
  __shared__ float Wt[32][132];
  __shared__ float Xs[32][68];
  __shared__ float T[64][133];
  const int tid = threadIdx.x;
  const int tx = tid & 15, ty = tid >> 4;
  const int p0 = blockIdx.x * 64;
  const int ro = blockIdx.y * 128;
  const int b = blockIdx.z;
  const float g0 = gamma[0];

  float acc[8][4];
#pragma unroll
  for (int i = 0; i < 8; ++i)
#pragma unroll
    for (int j = 0; j < 4; ++j) acc[i][j] = 0.f;

  for (int kk = 0; kk < DD; kk += 32) {
    __syncthreads();
#pragma unroll
    for (int u = 0; u < 4; ++u) {
      int e = tid + 256 * u;
      int c4 = (e & 7) * 4, r = e >> 3;
      float w[4]; ld4(w, &Wp[(ro + r) * DD + kk + c4]);
      Wt[c4 + 0][r] = w[0]; Wt[c4 + 1][r] = w[1];
      Wt[c4 + 2][r] = w[2]; Wt[c4 + 3][r] = w[3];
    }
    // ao[i][c]: load float4 along c, transpose into Xs[c][p]
#pragma unroll
    for (int u = 0; u < 2; ++u) {
      int e = tid + 256 * u;
      int p = e >> 3, c4 = (e & 7) * 4;
      float4 v = *(const float4*)&ao[((size_t)b * HW + p0 + p) * DD + kk + c4];
      Xs[c4 + 0][p] = v.x; Xs[c4 + 1][p] = v.y;
      Xs[c4 + 2][p] = v.z; Xs[c4 + 3][p] = v.w;
    }
    __syncthreads();
#pragma unroll 4
    for (int c = 0; c < 32; ++c) {
      float wa[8], xb[4];
      ld4(wa, &Wt[c][ty * 8]); ld4(wa + 4, &Wt[c][ty * 8 + 4]);
      ld4(xb, &Xs[c][tx * 4]);
#pragma unroll
      for (int rr = 0; rr < 8; ++rr)
#pragma unroll
        for (int pp = 0; pp < 4; ++pp) acc[rr][pp] += wa[rr] * xb[pp];
    }
  }
#pragma unroll
  for (int rr = 0; rr < 8; ++rr) {
    int r = ro + ty * 8 + rr;
    int idx = (b * CC + r) * HW + p0 + tx * 4;
    float4 t4 = *(const float4*)&tgt[idx];
    float bpv = bp[r];
    T[tx * 4 + 0][ty * 8 + rr] = t4.x + g0 * (acc[rr][0] + bpv);
    T[tx * 4 + 1][ty * 8 + rr] = t4.y + g0 * (acc[rr][1] + bpv);
    T[tx * 4 + 2][ty * 8 + rr] = t4.z + g0 * (acc[rr][2] + bpv);
    T[tx * 4 + 3][ty * 8 + rr] = t4.w + g0 * (acc[rr][3] + bpv);
  }
  __syncthreads();
  {
    int p = tid >> 2, cq = (tid & 3) * 32;
    int hh = p0 >> 6;
    unsigned* dst = (unsigned*)(Xn + ((((size_t)b * 66 + hh + 1) * 66) + 1 + p) * 768 + ro + cq);
#pragma unroll
    for (int e = 0; e < 16; ++e)
      dst[e] = pk2(T[p][cq + 2 * e], T[p][cq + 2 * e + 1]);
  }
}

// ---------------- K4b: upsample prev into Xn interior, channels [256,768)
__global__ __launch_bounds__(256) void k_pack(
    const float* __restrict__ prev, short* __restrict__ Xn)
{
  __shared__ float tile[64][65];
  const int tid = threadIdx.x;
  const int h = blockIdx.x;
  const int ci0 = blockIdx.y * 64;
  const int b = blockIdx.z;

  {
    int w = tid & 63, r = tid >> 6;
    for (int cs = r; cs < 64; cs += 4)
      tile[cs][w] = prev[((size_t)b * 512 + ci0 + cs) * 1024 + (h >> 1) * 32 + (w >> 1)];
  }
  __syncthreads();
  {
    int ci = tid & 63, wq = tid >> 6;
    for (int ws2 = wq; ws2 < 64; ws2 += 4)
      Xn[((((size_t)b * 66 + h + 1) * 66) + 1 + ws2) * 768 + 256 + ci0 + ci] = f2b(tile[ci][ws2]);
  }
}

// ---------------- K4c: weight repack Wc(256,768,3,3) f32 -> Wb(256,9,768) bf16
__global__ __launch_bounds__(256) void k_wb(
    const float* __restrict__ Wc, short* __restrict__ Wb)
{
  int i = blockIdx.x * 256 + threadIdx.x;
  int o = i / 6912;
  int rem = i - o * 6912;
  int khw = rem / 768;
  int ci = rem - khw * 768;
  Wb[i] = f2b(Wc[(size_t)o * 6912 + ci * 9 + khw]);
}

// ---------------- K5: 3x3 conv, R2 structure (64x2x4 grid, 2 blocks/CU,
// 2 barriers/stage) with staging switched to global_load_lds DMA:
// LDS tiles LINEAR stride-64; read conflict broken by both-sides XOR:
//   LDS slot (row, g) <- global granule (g ^ (row&7)); read G at (G ^ (row&7)).
__global__ __launch_bounds__(256, 2) void k_conv_mfma(
    const short* __restrict__ Xn,   // (B,66,66,768) bf16, guard ring zero
    const short* __restrict__ Wb,   // (256,9,768) bf16
    const float* __restrict__ bcw,
    short* __restrict__ cb)         // (B,256,4096) bf16
{
  __shared__ __align__(16) short Wl[384 * 64];  // 48 KB, [kw*128+cout][64ci]
  __shared__ __align__(16) short Xl[66 * 64];   // 8.25 KB, [px][64ci]
  const int tid = threadIdx.x;
  const int wv = tid >> 6;
  const int lane = tid & 63;
  const int t = lane & 15, q = lane >> 4;
  const int h = blockIdx.x;
  const int m0blk = blockIdx.y * 128;
  const int b = blockIdx.z;

  const f32x4 zf = {0.f, 0.f, 0.f, 0.f};
  f32x4 acc[2][4];
#pragma unroll
  for (int mt = 0; mt < 2; ++mt)
#pragma unroll
    for (int nt = 0; nt < 4; ++nt) acc[mt][nt] = zf;

  for (int kh = 0; kh < 3; ++kh) {
    const short* wsrc = Wb + (size_t)m0blk * 6912 + (kh * 3) * 768;
    const short* xsrc = Xn + ((size_t)b * 66 + h + kh) * 66 * 768;
    for (int ci0 = 0; ci0 < 768; ci0 += 64) {
      // stage W: 384 rows x 8 granules(16B) = 3072; 12 DMA per thread
#pragma unroll
      for (int r = 0; r < 12; ++r) {
        int e = tid + (r << 8);
        int g = e & 7, row = e >> 3;
        int kw = row >> 7, cout = row & 127;
        int gs = g ^ (row & 7);
        gl16(wsrc + (size_t)cout * 6912 + kw * 768 + ci0 + gs * 8, Wl + e * 8);
      }
      // stage X: 66 rows x 8 granules = 528
#pragma unroll
      for (int r = 0; r < 3; ++r) {
        int e = tid + (r << 8);
        if (e < 528) {
          int g = e & 7, px = e >> 3;
          int gs = g ^ (px & 7);
          gl16(xsrc + (size_t)px * 768 + ci0 + gs * 8, Xl + e * 8);
        }
      }
      __syncthreads();
#pragma unroll
      for (int kw = 0; kw < 3; ++kw) {
        bf16x8 af[2][2], bfr[4][2];
#pragma unroll
        for (int kk = 0; kk < 2; ++kk) {
#pragma unroll
          for (int mt = 0; mt < 2; ++mt) {
            int row = kw * 128 + wv * 32 + mt * 16 + t;
            int g = (kk * 4 + q) ^ (row & 7);
            af[mt][kk] = *(const bf16x8*)(Wl + row * 64 + g * 8);
          }
#pragma unroll
          for (int nt = 0; nt < 4; ++nt) {
            int row = nt * 16 + t + kw;
            int g = (kk * 4 + q) ^ (row & 7);
            bfr[nt][kk] = *(const bf16x8*)(Xl + row * 64 + g * 8);
          }
        }
#pragma unroll
        for (int kk = 0; kk < 2; ++kk)
#pragma unroll
          for (int mt = 0; mt < 2; ++mt)
#pragma unroll
            for (int nt = 0; nt < 4; ++nt)
              acc[mt][nt] = __builtin_amdgcn_mfma_f32_16x16x32_bf16(
                  af[mt][kk], bfr[nt][kk], acc[mt][nt], 0, 0, 0);
      }
      __syncthreads();
    }
  }
  // D mapping: outch = m0blk + wv*32 + mt*16 + q*4 + r ; px = nt*16 + t
#pragma unroll
  for (int mt = 0; mt < 2; ++mt) {
    int om = m0blk + wv * 32 + mt * 16 + q * 4;
#pragma unroll
    for (int r = 0; r < 4; ++r) {
      float bias = bcw[om + r];
      short* orow = cb + ((size_t)b * CC + om + r) * HW + h * 64;
#pragma unroll
      for (int nt = 0; nt < 4; ++nt)
        orow[nt * 16 + t] = f2b(acc[mt][nt][r] + bias);
    }
  }
}

// ---------------- K6: InstanceNorm (biased var, eps=1e-5) + ReLU; bf16 in, f32 out
__global__ __launch_bounds__(256) void k_inorm(
    const short* __restrict__ cb, float* __restrict__ out)
{
  __shared__ float buf[4096];
  __shared__ float red[8];
  const int tid = threadIdx.x;
  const int ch = blockIdx.x;
  const short* srcp = cb + (size_t)ch * HW;

  float s = 0.f, sq = 0.f;
#pragma unroll
  for (int u = 0; u < 2; ++u) {
    int sidx = u * 2048 + tid * 8;
    uint4 pk = *(const uint4*)(srcp + sidx);
    float f[8];
    f[0] = __uint_as_float(pk.x << 16); f[1] = __uint_as_float(pk.x & 0xffff0000u);
    f[2] = __uint_as_float(pk.y << 16); f[3] = __uint_as_float(pk.y & 0xffff0000u);
    f[4] = __uint_as_float(pk.z << 16); f[5] = __uint_as_float(pk.z & 0xffff0000u);
    f[6] = __uint_as_float(pk.w << 16); f[7] = __uint_as_float(pk.w & 0xffff0000u);
#pragma unroll
    for (int e = 0; e < 8; ++e) {
      buf[sidx + e] = f[e];
      s += f[e];
      sq += f[e] * f[e];
    }
  }
#pragma unroll
  for (int m = 32; m >= 1; m >>= 1) {
    s  += __shfl_xor(s, m, 64);
    sq += __shfl_xor(sq, m, 64);
  }
  if ((tid & 63) == 0) { red[tid >> 6] = s; red[4 + (tid >> 6)] = sq; }
  __syncthreads();
  if (tid == 0) {
    float S = red[0] + red[1] + red[2] + red[3];
    float Q = red[4] + red[5] + red[6] + red[7];
    float mean = S * (1.f / HW);
    float var = Q * (1.f / HW) - mean * mean;
    red[0] = mean;
    red[1] = rsqrtf(var + 1e-5f);
  }
  __syncthreads();
  const float mean = red[0], rs = red[1];
#pragma unroll
  for (int u = 0; u < 4; ++u) {
    int idx = u * 1024 + tid * 4;
    float4 v = *(const float4*)&buf[idx];
    float4 o4 = make_float4(fmaxf((v.x - mean) * rs, 0.f),
                            fmaxf((v.y - mean) * rs, 0.f),
                            fmaxf((v.z - mean) * rs, 0.f),
                            fmaxf((v.w - mean) * rs, 0.f));
    *(float4*)&out[(size_t)ch * HW + idx] = o4;
  }
}

extern "C" void kernel_launch(void* const* d_in, const int* in_sizes, int n_in,
                              void* d_out, int out_size, void* d_ws, size_t ws_size,
                              hipStream_t stream) {
  const float* src  = (const float*)d_in[0];
  const float* tgt  = (const float*)d_in[1];
  const float* prev = (const float*)d_in[2];
  const float* Wq = (const float*)d_in[3];  const float* bq = (const float*)d_in[4];
  const float* Wk = (const float*)d_in[5];  const float* bk = (const float*)d_in[6];
  const float* Wv = (const float*)d_in[7];  const float* bv = (const float*)d_in[8];
  const float* Wp = (const float*)d_in[9];  const float* bp = (const float*)d_in[10];
  const float* gamma = (const float*)d_in[11];
  const float* Wc = (const float*)d_in[12]; const float* bcw = (const float*)d_in[13];

  float* ws = (float*)d_ws;
  // float-unit offsets; lifetimes:
  short* qb = (short*)ws;                 // [0, 1048576)        dead after k_attn2
  short* kb = (short*)(ws + 1048576);     // [1048576, 2097152)  dead after k_attn2
  short* vb = (short*)(ws + 2097152);     // [2097152, 3145728)  dead after k_vs
  float* rl = ws + 3145728;               // [3145728, 3162112)  dead after k_vs
  short* vs = (short*)(ws + 3162112);     // [3162112, 4210688)  dead after k_attn2
  short* Xn = (short*)ws;                 // [0, 6690816)  (B,66,66,768) over qb/kb/vb/rl/vs
  float* ao = ws + 6690816;               // [6690816, 8787968)  [B][HW][DD], zeroed before attn2
  short* cb = (short*)(ws + 6690816);     // over ao (ao dead after k_proj)
  short* Wb = (short*)(ws + 8787968);     // [8787968, 9672704)
  // high-water: 9,672,704 floats = 38.7 MB

  k_qkv_mfma<<<dim3(64, 3, BB), 256, 0, stream>>>(src, tgt, Wq, bq, Wk, bk, Wv, bv, qb, kb, vb);
  hipMemsetAsync(rl, 0, (size_t)BB * HW * 4, stream);
  k_lsum2<<<dim3(64, 4, BB), 256, 0, stream>>>(qb, kb, rl);
  k_vs   <<<dim3(2048),      256, 0, stream>>>(vb, rl, vs);
  hipMemsetAsync(ao, 0, (size_t)2097152 * 4, stream);
  k_attn2<<<dim3(32, 4, BB), 256, 0, stream>>>(qb, kb, vs, ao);
  // Xn overlaps qb/kb/vb/rl/vs -> zero only after k_attn2 (also zeroes guard ring)
  hipMemsetAsync(Xn, 0, (size_t)BB * 66 * 66 * 768 * 2, stream);
  k_proj <<<dim3(64, 2, BB), 256, 0, stream>>>(ao, tgt, Wp, bp, gamma, Xn);
  k_pack <<<dim3(64, 8, BB), 256, 0, stream>>>(prev, Xn);
  k_wb   <<<dim3(6912),      256, 0, stream>>>(Wc, Wb);
  k_conv_mfma<<<dim3(64, 2, BB), 256, 0, stream>>>(Xn, Wb, bcw, cb);
  k_inorm<<<dim3(1024),      256, 0, stream>>>(cb, (float*)d_out);
}